// Round 8
// baseline (403.276 us; speedup 1.0000x reference)
//
#include <hip/hip_runtime.h>
#include <hip/hip_bf16.h>
#include <stdint.h>

// Problem constants
#define S_LEN 2048
#define EMB   1024
#define NH    16
#define DH    64
#define BATCH 2

typedef short bf16x8 __attribute__((ext_vector_type(8)));
typedef float f32x4  __attribute__((ext_vector_type(4)));

__device__ __forceinline__ unsigned short f2bf(float f) {
    union { float f; unsigned int u; } v; v.f = f;
    unsigned int r = v.u + 0x7FFFu + ((v.u >> 16) & 1u);
    return (unsigned short)(r >> 16);
}

__device__ __forceinline__ bf16x8 load8f_to_bf(const float* __restrict__ p) {
    const float4* p4 = (const float4*)p;
    float4 x0 = p4[0];
    float4 x1 = p4[1];
    bf16x8 r;
    r[0] = (short)f2bf(x0.x); r[1] = (short)f2bf(x0.y);
    r[2] = (short)f2bf(x0.z); r[3] = (short)f2bf(x0.w);
    r[4] = (short)f2bf(x1.x); r[5] = (short)f2bf(x1.y);
    r[6] = (short)f2bf(x1.z); r[7] = (short)f2bf(x1.w);
    return r;
}

// ---------------------------------------------------------------------------
// Kernel 0: vectorized f32 -> bf16 conversion of x, Wq, Wk, Wv, Er.
// ---------------------------------------------------------------------------
__global__ __launch_bounds__(256) void cvt_bf16(
    const float* __restrict__ x,  const float* __restrict__ wq,
    const float* __restrict__ wk, const float* __restrict__ wv,
    const float* __restrict__ er,
    unsigned short* __restrict__ xb, unsigned short* __restrict__ wb,
    unsigned short* __restrict__ erb)
{
    const int NX = 4194304 / 8, NW = 1048576 / 8, NE = 131072 / 8;
    const int total = NX + 3 * NW + NE;
    for (int i8 = blockIdx.x * 256 + threadIdx.x; i8 < total; i8 += gridDim.x * 256) {
        const float* src; unsigned short* dst; int off;
        if      (i8 < NX)          { src = x;  dst = xb;            off = i8; }
        else if (i8 < NX + NW)     { src = wq; dst = wb;            off = i8 - NX; }
        else if (i8 < NX + 2 * NW) { src = wk; dst = wb + 1048576;  off = i8 - NX - NW; }
        else if (i8 < NX + 3 * NW) { src = wv; dst = wb + 2097152;  off = i8 - NX - 2 * NW; }
        else                       { src = er; dst = erb;           off = i8 - NX - 3 * NW; }
        ((bf16x8*)dst)[off] = load8f_to_bf(src + (size_t)off * 8);
    }
}

// ---------------------------------------------------------------------------
// Kernel 1 (fast path): QKV projection from pre-converted bf16 inputs.
// ---------------------------------------------------------------------------
__global__ __launch_bounds__(256) void proj_kernel_bf(
    const unsigned short* __restrict__ xb, const unsigned short* __restrict__ wb,
    unsigned short* __restrict__ Qb, unsigned short* __restrict__ Kb,
    unsigned short* __restrict__ Vt)
{
    const int tid  = threadIdx.x;
    const int lane = tid & 63;
    const int w    = tid >> 6;
    const int wr   = w >> 1;
    const int wc   = w & 1;
    const int m0   = blockIdx.x * 128 + wr * 64;
    const int c0   = blockIdx.y * 128 + wc * 64;
    const int wsel = c0 >> 10;
    const int f0   = c0 & 1023;
    const unsigned short* __restrict__ W = wb + (size_t)wsel * 1048576;

    const int lr = lane & 15;
    const int lk = (lane >> 4) * 8;

    f32x4 acc[4][4];
#pragma unroll
    for (int i = 0; i < 4; i++)
#pragma unroll
        for (int n = 0; n < 4; n++) acc[i][n] = (f32x4){0.f, 0.f, 0.f, 0.f};

    for (int k0 = 0; k0 < 1024; k0 += 32) {
        bf16x8 a[4], b[4];
#pragma unroll
        for (int i = 0; i < 4; i++)
            a[i] = *(const bf16x8*)&xb[(size_t)(m0 + i * 16 + lr) * 1024 + k0 + lk];
#pragma unroll
        for (int n = 0; n < 4; n++)
            b[n] = *(const bf16x8*)&W[(size_t)(f0 + n * 16 + lr) * 1024 + k0 + lk];
#pragma unroll
        for (int i = 0; i < 4; i++)
#pragma unroll
            for (int n = 0; n < 4; n++)
                acc[i][n] = __builtin_amdgcn_mfma_f32_16x16x32_bf16(a[i], b[n], acc[i][n], 0, 0, 0);
    }

    const int g = lane >> 4;
#pragma unroll
    for (int i = 0; i < 4; i++) {
#pragma unroll
        for (int n = 0; n < 4; n++) {
#pragma unroll
            for (int j = 0; j < 4; j++) {
                int row_m = m0 + i * 16 + g * 4 + j;
                int c     = c0 + n * 16 + lr;
                int f     = c & 1023;
                int h     = f >> 6;
                int dd    = f & 63;
                int bb    = row_m >> 11;
                int s     = row_m & 2047;
                int bh    = bb * 16 + h;
                unsigned short bv = f2bf(acc[i][n][j]);
                if (wsel == 0)      Qb[((size_t)bh * 2048 + s) * 64 + dd] = bv;
                else if (wsel == 1) Kb[((size_t)bh * 2048 + s) * 64 + dd] = bv;
                else                Vt[((size_t)bh * 64 + dd) * 2048 + s] = bv;
            }
        }
    }
}

// ---------------------------------------------------------------------------
// Kernel 1 (fallback): f32 inputs with in-loop convert.
// ---------------------------------------------------------------------------
__global__ __launch_bounds__(256) void proj_kernel_f32(
    const float* __restrict__ x,
    const float* __restrict__ Wq, const float* __restrict__ Wk,
    const float* __restrict__ Wv,
    unsigned short* __restrict__ Qb, unsigned short* __restrict__ Kb,
    unsigned short* __restrict__ Vt)
{
    const int tid  = threadIdx.x;
    const int lane = tid & 63;
    const int w    = tid >> 6;
    const int wr   = w >> 1;
    const int wc   = w & 1;
    const int m0   = blockIdx.x * 128 + wr * 64;
    const int c0   = blockIdx.y * 128 + wc * 64;
    const int wsel = c0 >> 10;
    const int f0   = c0 & 1023;
    const float* __restrict__ W = (wsel == 0) ? Wq : (wsel == 1) ? Wk : Wv;

    const int lr = lane & 15;
    const int lk = (lane >> 4) * 8;

    f32x4 acc[4][4];
#pragma unroll
    for (int i = 0; i < 4; i++)
#pragma unroll
        for (int n = 0; n < 4; n++) acc[i][n] = (f32x4){0.f, 0.f, 0.f, 0.f};

    for (int k0 = 0; k0 < 1024; k0 += 32) {
        bf16x8 a[4], b[4];
#pragma unroll
        for (int i = 0; i < 4; i++)
            a[i] = load8f_to_bf(&x[(size_t)(m0 + i * 16 + lr) * 1024 + k0 + lk]);
#pragma unroll
        for (int n = 0; n < 4; n++)
            b[n] = load8f_to_bf(&W[(size_t)(f0 + n * 16 + lr) * 1024 + k0 + lk]);
#pragma unroll
        for (int i = 0; i < 4; i++)
#pragma unroll
            for (int n = 0; n < 4; n++)
                acc[i][n] = __builtin_amdgcn_mfma_f32_16x16x32_bf16(a[i], b[n], acc[i][n], 0, 0, 0);
    }

    const int g = lane >> 4;
#pragma unroll
    for (int i = 0; i < 4; i++) {
#pragma unroll
        for (int n = 0; n < 4; n++) {
#pragma unroll
            for (int j = 0; j < 4; j++) {
                int row_m = m0 + i * 16 + g * 4 + j;
                int c     = c0 + n * 16 + lr;
                int f     = c & 1023;
                int h     = f >> 6;
                int dd    = f & 63;
                int bb    = row_m >> 11;
                int s     = row_m & 2047;
                int bh    = bb * 16 + h;
                unsigned short bv = f2bf(acc[i][n][j]);
                if (wsel == 0)      Qb[((size_t)bh * 2048 + s) * 64 + dd] = bv;
                else if (wsel == 1) Kb[((size_t)bh * 2048 + s) * 64 + dd] = bv;
                else                Vt[((size_t)bh * 64 + dd) * 2048 + s] = bv;
            }
        }
    }
}

__global__ void cvt_er(const float* __restrict__ Er, unsigned short* __restrict__ Erb, int n)
{
    int i = blockIdx.x * 256 + threadIdx.x;
    if (i < n) Erb[i] = f2bf(Er[i]);
}

// ---------------------------------------------------------------------------
// Kernel 2: flash attention, swapped-operand, single-wave blocks.
// Grid 4096 = (xcd:3b | b2:2b | strip:2b | qt:5b), one q-tile per block,
// heavy tiles dispatched first (dynamic load balance at 16 blocks/CU).
// __launch_bounds__(64,4): 4 waves/SIMD (VGPR<=128, fits per r7).
// Softmax critical-path cuts:
//  - per-lane PARTIAL lsum; cross-lane reduce ONCE in epilogue (valid since
//    mrow is row-uniform by induction).
//  - T13 defer-max thr=4: skip row-max reduce + o-rescale unless
//    __any(partial_max > mrow+4); P bounded by 2^4, safe in bf16.
// ---------------------------------------------------------------------------
__global__ __launch_bounds__(64, 4) void attn_kernel(
    const unsigned short* __restrict__ Qb, const unsigned short* __restrict__ Kb,
    const unsigned short* __restrict__ Vt, const unsigned short* __restrict__ Erb,
    float* __restrict__ out)
{
    __shared__ __align__(16) float          Rt2[80][18];
    __shared__ __align__(16) unsigned short Pl[16][72];

    const int lane = threadIdx.x & 63;

    const int i0    = blockIdx.x;
    const int xcd   = i0 & 7;            // XCD pin: bh in {4*xcd..4*xcd+3}
    const int b2    = (i0 >> 3) & 3;
    const int strip = (i0 >> 5) & 3;
    const int qt    = 31 - (i0 >> 7);    // heavy first
    const int bh    = (xcd << 2) | b2;

    const int lr = lane & 15;
    const int g  = lane >> 4;
    const int lk = g * 8;

    const unsigned short* __restrict__ Qrow = Qb + (size_t)bh * 2048 * 64;
    const unsigned short* __restrict__ Krow = Kb + (size_t)bh * 2048 * 64;
    const unsigned short* __restrict__ Vrow = Vt + (size_t)bh * 64 * 2048;

    const float SCL = 0.125f * 1.44269504089f;  // (1/sqrt(64)) * log2(e)
    const int bb = bh >> 4;
    const int h  = bh & 15;

    const int q0w = qt * 64 + strip * 16;

    bf16x8 aq[2];
    aq[0] = *(const bf16x8*)&Qrow[(size_t)(q0w + lr) * 64 + 0  + lk];
    aq[1] = *(const bf16x8*)&Qrow[(size_t)(q0w + lr) * 64 + 32 + lk];

    f32x4 o[4];
#pragma unroll
    for (int n = 0; n < 4; n++) o[n] = (f32x4){0.f, 0.f, 0.f, 0.f};
    float mrow = -1e30f, lsumP = 0.f;    // lsumP: per-lane PARTIAL row sum

    auto loadK = [&](bf16x8 (&kb)[2][4], int kt) {
        const int k0 = kt * 64;
#pragma unroll
        for (int kk = 0; kk < 2; kk++)
#pragma unroll
            for (int n = 0; n < 4; n++)
                kb[kk][n] = *(const bf16x8*)&Krow[(size_t)(k0 + n * 16 + lr) * 64 + kk * 32 + lk];
    };

    auto body = [&](const bf16x8 (&kb)[2][4], int kt) {
        const int k0 = kt * 64;
        const int rbase = 2047 + k0 - q0w - 15;   // >= 0 always

        // ---- S^T = K·Q^T and R^T = Er·Q^T ----
        f32x4 s[4], r[5];
#pragma unroll
        for (int n = 0; n < 4; n++) s[n] = (f32x4){0.f, 0.f, 0.f, 0.f};
#pragma unroll
        for (int n = 0; n < 5; n++) r[n] = (f32x4){0.f, 0.f, 0.f, 0.f};
#pragma unroll
        for (int kk = 0; kk < 2; kk++) {
            bf16x8 be[5];
#pragma unroll
            for (int n = 0; n < 5; n++) {
                int rr = rbase + n * 16 + lr;
                rr = rr > 2047 ? 2047 : rr;
                be[n] = *(const bf16x8*)&Erb[(size_t)rr * 64 + kk * 32 + lk];
            }
#pragma unroll
            for (int n = 0; n < 4; n++)
                s[n] = __builtin_amdgcn_mfma_f32_16x16x32_bf16(kb[kk][n], aq[kk], s[n], 0, 0, 0);
#pragma unroll
            for (int n = 0; n < 5; n++)
                r[n] = __builtin_amdgcn_mfma_f32_16x16x32_bf16(be[n], aq[kk], r[n], 0, 0, 0);
        }

        // ---- V loads issued early (hide under LDS/softmax) ----
        bf16x8 vv[2][4];
#pragma unroll
        for (int kk = 0; kk < 2; kk++)
#pragma unroll
            for (int n = 0; n < 4; n++)
                vv[kk][n] = *(const bf16x8*)&Vrow[(size_t)(n * 16 + lr) * 2048 + k0 + kk * 32 + lk];

        // ---- stash QEr window: same-column shift, no transpose ----
#pragma unroll
        for (int n = 0; n < 5; n++)
#pragma unroll
            for (int j = 0; j < 4; j++)
                Rt2[n * 16 + g * 4 + j][lr] = r[n][j];

        __syncthreads();   // FENCE: Rt2 writes -> cross-lane reads

        // ---- combine + mask; per-lane partial max only ----
        float pmax = -1e30f;
#pragma unroll
        for (int n = 0; n < 4; n++) {
#pragma unroll
            for (int j = 0; j < 4; j++) {
                int w  = n * 16 + g * 4 + j + 15 - lr;     // window pos
                float sc = (s[n][j] + Rt2[w][lr]) * SCL;
                if (k0 + n * 16 + g * 4 + j > q0w + lr) sc = -1e30f;
                s[n][j] = sc;
                pmax = fmaxf(pmax, sc);
            }
        }

        // ---- T13: only reduce + rescale when the row max actually grows ----
        if (__any(pmax > mrow + 4.0f)) {
            pmax = fmaxf(pmax, __shfl_xor(pmax, 16));
            pmax = fmaxf(pmax, __shfl_xor(pmax, 32));
            float mn   = fmaxf(mrow, pmax);
            float corr = exp2f(mrow - mn);
            mrow = mn;
            lsumP *= corr;
#pragma unroll
            for (int j = 0; j < 4; j++) {
                float cj = __shfl(corr, g * 4 + j);
#pragma unroll
                for (int n = 0; n < 4; n++) o[n][j] *= cj;
            }
        }
        float rs = 0.f;
#pragma unroll
        for (int n = 0; n < 4; n++) {
#pragma unroll
            for (int j = 0; j < 4; j++) {
                float pv = exp2f(s[n][j] - mrow);
                rs += pv;
                Pl[lr][n * 16 + g * 4 + j] = f2bf(pv);
            }
        }
        lsumP += rs;   // partial (this lane's 16 k-columns of row lr)

        __syncthreads();   // FENCE: Pl writes -> cross-lane A-frag reads

        // ---- P @ V ----
#pragma unroll
        for (int kk = 0; kk < 2; kk++) {
            bf16x8 pa = *(const bf16x8*)&Pl[lr][kk * 32 + lk];
#pragma unroll
            for (int n = 0; n < 4; n++)
                o[n] = __builtin_amdgcn_mfma_f32_16x16x32_bf16(pa, vv[kk][n], o[n], 0, 0, 0);
        }
    };

    // K register double-buffer, ping-pong with static buffers
    bf16x8 kA[2][4], kB[2][4];
    loadK(kA, 0);
    int kt = 0;
    while (true) {
        if (kt + 1 <= qt) loadK(kB, kt + 1);
        body(kA, kt);
        kt++;
        if (kt > qt) break;
        if (kt + 1 <= qt) loadK(kA, kt + 1);
        body(kB, kt);
        kt++;
        if (kt > qt) break;
    }

    // ---- epilogue: reduce partial lsum across the 4 g-lanes, then store ----
    float ls = lsumP;
    ls += __shfl_xor(ls, 16);
    ls += __shfl_xor(ls, 32);
    float linv = 1.0f / ls;              // full row-lr sum
#pragma unroll
    for (int j = 0; j < 4; j++) {
        float lj = __shfl(linv, g * 4 + j);
#pragma unroll
        for (int n = 0; n < 4; n++) {
            int row = q0w + g * 4 + j;
            int col = h * 64 + n * 16 + lr;
            out[((size_t)bb * 2048 + row) * 1024 + col] = o[n][j] * lj;
        }
    }
}

// ---------------------------------------------------------------------------
extern "C" void kernel_launch(void* const* d_in, const int* in_sizes, int n_in,
                              void* d_out, int out_size, void* d_ws, size_t ws_size,
                              hipStream_t stream)
{
    const float* x  = (const float*)d_in[0];
    const float* Wq = (const float*)d_in[1];
    const float* Wk = (const float*)d_in[2];
    const float* Wv = (const float*)d_in[3];
    const float* Er = (const float*)d_in[4];
    float* out = (float*)d_out;   // f32 output (reference returns jnp.float32)

    char* ws = (char*)d_ws;
    const size_t MB = 1024 * 1024;
    unsigned short* Qb  = (unsigned short*)(ws);            // 8 MB
    unsigned short* Kb  = (unsigned short*)(ws + 8  * MB);  // 8 MB
    unsigned short* Vt  = (unsigned short*)(ws + 16 * MB);  // 8 MB
    unsigned short* Erb = (unsigned short*)(ws + 24 * MB);  // 256 KB
    unsigned short* xb  = (unsigned short*)(ws + 25 * MB);  // 8 MB
    unsigned short* wb  = (unsigned short*)(ws + 33 * MB);  // 6 MB  (total 39 MB)

    if (ws_size >= (size_t)39 * MB) {
        cvt_bf16<<<dim3(1024), dim3(256), 0, stream>>>(x, Wq, Wk, Wv, Er, xb, wb, Erb);
        proj_kernel_bf<<<dim3(32, 24), dim3(256), 0, stream>>>(xb, wb, Qb, Kb, Vt);
    } else {
        cvt_er<<<dim3(512), dim3(256), 0, stream>>>(Er, Erb, 2048 * 64);
        proj_kernel_f32<<<dim3(32, 24), dim3(256), 0, stream>>>(x, Wq, Wk, Wv, Qb, Kb, Vt);
    }
    attn_kernel<<<dim3(4096), dim3(64), 0, stream>>>(Qb, Kb, Vt, Erb, out);
}

// Round 9
// 373.321 us; speedup vs baseline: 1.0802x; 1.0802x over previous
//
#include <hip/hip_runtime.h>
#include <hip/hip_bf16.h>
#include <stdint.h>

// Problem constants
#define S_LEN 2048
#define EMB   1024
#define NH    16
#define DH    64
#define BATCH 2

typedef short bf16x8 __attribute__((ext_vector_type(8)));
typedef short bf16x4 __attribute__((ext_vector_type(4)));
typedef float f32x4  __attribute__((ext_vector_type(4)));

__device__ __forceinline__ unsigned short f2bf(float f) {
    union { float f; unsigned int u; } v; v.f = f;
    unsigned int r = v.u + 0x7FFFu + ((v.u >> 16) & 1u);
    return (unsigned short)(r >> 16);
}

__device__ __forceinline__ bf16x8 load8f_to_bf(const float* __restrict__ p) {
    const float4* p4 = (const float4*)p;
    float4 x0 = p4[0];
    float4 x1 = p4[1];
    bf16x8 r;
    r[0] = (short)f2bf(x0.x); r[1] = (short)f2bf(x0.y);
    r[2] = (short)f2bf(x0.z); r[3] = (short)f2bf(x0.w);
    r[4] = (short)f2bf(x1.x); r[5] = (short)f2bf(x1.y);
    r[6] = (short)f2bf(x1.z); r[7] = (short)f2bf(x1.w);
    return r;
}

// ---------------------------------------------------------------------------
// Kernel 0: vectorized f32 -> bf16 conversion of x, Wq, Wk, Wv, Er.
// ---------------------------------------------------------------------------
__global__ __launch_bounds__(256) void cvt_bf16(
    const float* __restrict__ x,  const float* __restrict__ wq,
    const float* __restrict__ wk, const float* __restrict__ wv,
    const float* __restrict__ er,
    unsigned short* __restrict__ xb, unsigned short* __restrict__ wb,
    unsigned short* __restrict__ erb)
{
    const int NX = 4194304 / 8, NW = 1048576 / 8, NE = 131072 / 8;
    const int total = NX + 3 * NW + NE;
    for (int i8 = blockIdx.x * 256 + threadIdx.x; i8 < total; i8 += gridDim.x * 256) {
        const float* src; unsigned short* dst; int off;
        if      (i8 < NX)          { src = x;  dst = xb;            off = i8; }
        else if (i8 < NX + NW)     { src = wq; dst = wb;            off = i8 - NX; }
        else if (i8 < NX + 2 * NW) { src = wk; dst = wb + 1048576;  off = i8 - NX - NW; }
        else if (i8 < NX + 3 * NW) { src = wv; dst = wb + 2097152;  off = i8 - NX - 2 * NW; }
        else                       { src = er; dst = erb;           off = i8 - NX - 3 * NW; }
        ((bf16x8*)dst)[off] = load8f_to_bf(src + (size_t)off * 8);
    }
}

// ---------------------------------------------------------------------------
// Kernel 1 (fast path): QKV projection from pre-converted bf16 inputs.
// ---------------------------------------------------------------------------
__global__ __launch_bounds__(256) void proj_kernel_bf(
    const unsigned short* __restrict__ xb, const unsigned short* __restrict__ wb,
    unsigned short* __restrict__ Qb, unsigned short* __restrict__ Kb,
    unsigned short* __restrict__ Vt)
{
    const int tid  = threadIdx.x;
    const int lane = tid & 63;
    const int w    = tid >> 6;
    const int wr   = w >> 1;
    const int wc   = w & 1;
    const int m0   = blockIdx.x * 128 + wr * 64;
    const int c0   = blockIdx.y * 128 + wc * 64;
    const int wsel = c0 >> 10;
    const int f0   = c0 & 1023;
    const unsigned short* __restrict__ W = wb + (size_t)wsel * 1048576;

    const int lr = lane & 15;
    const int lk = (lane >> 4) * 8;

    f32x4 acc[4][4];
#pragma unroll
    for (int i = 0; i < 4; i++)
#pragma unroll
        for (int n = 0; n < 4; n++) acc[i][n] = (f32x4){0.f, 0.f, 0.f, 0.f};

    for (int k0 = 0; k0 < 1024; k0 += 32) {
        bf16x8 a[4], b[4];
#pragma unroll
        for (int i = 0; i < 4; i++)
            a[i] = *(const bf16x8*)&xb[(size_t)(m0 + i * 16 + lr) * 1024 + k0 + lk];
#pragma unroll
        for (int n = 0; n < 4; n++)
            b[n] = *(const bf16x8*)&W[(size_t)(f0 + n * 16 + lr) * 1024 + k0 + lk];
#pragma unroll
        for (int i = 0; i < 4; i++)
#pragma unroll
            for (int n = 0; n < 4; n++)
                acc[i][n] = __builtin_amdgcn_mfma_f32_16x16x32_bf16(a[i], b[n], acc[i][n], 0, 0, 0);
    }

    const int g = lane >> 4;
#pragma unroll
    for (int i = 0; i < 4; i++) {
#pragma unroll
        for (int n = 0; n < 4; n++) {
#pragma unroll
            for (int j = 0; j < 4; j++) {
                int row_m = m0 + i * 16 + g * 4 + j;
                int c     = c0 + n * 16 + lr;
                int f     = c & 1023;
                int h     = f >> 6;
                int dd    = f & 63;
                int bb    = row_m >> 11;
                int s     = row_m & 2047;
                int bh    = bb * 16 + h;
                unsigned short bv = f2bf(acc[i][n][j]);
                if (wsel == 0)      Qb[((size_t)bh * 2048 + s) * 64 + dd] = bv;
                else if (wsel == 1) Kb[((size_t)bh * 2048 + s) * 64 + dd] = bv;
                else                Vt[((size_t)bh * 64 + dd) * 2048 + s] = bv;
            }
        }
    }
}

// ---------------------------------------------------------------------------
// Kernel 1 (fallback): f32 inputs with in-loop convert.
// ---------------------------------------------------------------------------
__global__ __launch_bounds__(256) void proj_kernel_f32(
    const float* __restrict__ x,
    const float* __restrict__ Wq, const float* __restrict__ Wk,
    const float* __restrict__ Wv,
    unsigned short* __restrict__ Qb, unsigned short* __restrict__ Kb,
    unsigned short* __restrict__ Vt)
{
    const int tid  = threadIdx.x;
    const int lane = tid & 63;
    const int w    = tid >> 6;
    const int wr   = w >> 1;
    const int wc   = w & 1;
    const int m0   = blockIdx.x * 128 + wr * 64;
    const int c0   = blockIdx.y * 128 + wc * 64;
    const int wsel = c0 >> 10;
    const int f0   = c0 & 1023;
    const float* __restrict__ W = (wsel == 0) ? Wq : (wsel == 1) ? Wk : Wv;

    const int lr = lane & 15;
    const int lk = (lane >> 4) * 8;

    f32x4 acc[4][4];
#pragma unroll
    for (int i = 0; i < 4; i++)
#pragma unroll
        for (int n = 0; n < 4; n++) acc[i][n] = (f32x4){0.f, 0.f, 0.f, 0.f};

    for (int k0 = 0; k0 < 1024; k0 += 32) {
        bf16x8 a[4], b[4];
#pragma unroll
        for (int i = 0; i < 4; i++)
            a[i] = load8f_to_bf(&x[(size_t)(m0 + i * 16 + lr) * 1024 + k0 + lk]);
#pragma unroll
        for (int n = 0; n < 4; n++)
            b[n] = load8f_to_bf(&W[(size_t)(f0 + n * 16 + lr) * 1024 + k0 + lk]);
#pragma unroll
        for (int i = 0; i < 4; i++)
#pragma unroll
            for (int n = 0; n < 4; n++)
                acc[i][n] = __builtin_amdgcn_mfma_f32_16x16x32_bf16(a[i], b[n], acc[i][n], 0, 0, 0);
    }

    const int g = lane >> 4;
#pragma unroll
    for (int i = 0; i < 4; i++) {
#pragma unroll
        for (int n = 0; n < 4; n++) {
#pragma unroll
            for (int j = 0; j < 4; j++) {
                int row_m = m0 + i * 16 + g * 4 + j;
                int c     = c0 + n * 16 + lr;
                int f     = c & 1023;
                int h     = f >> 6;
                int dd    = f & 63;
                int bb    = row_m >> 11;
                int s     = row_m & 2047;
                int bh    = bb * 16 + h;
                unsigned short bv = f2bf(acc[i][n][j]);
                if (wsel == 0)      Qb[((size_t)bh * 2048 + s) * 64 + dd] = bv;
                else if (wsel == 1) Kb[((size_t)bh * 2048 + s) * 64 + dd] = bv;
                else                Vt[((size_t)bh * 64 + dd) * 2048 + s] = bv;
            }
        }
    }
}

__global__ void cvt_er(const float* __restrict__ Er, unsigned short* __restrict__ Erb, int n)
{
    int i = blockIdx.x * 256 + threadIdx.x;
    if (i < n) Erb[i] = f2bf(Er[i]);
}

// ---------------------------------------------------------------------------
// Kernel 2: flash attention, swapped-operand, register-resident P.
// Layout identity: lane (lr,g) holds P[q=lr][k=16n+4g+j] == the A-fragment of
// mfma_f32_16x16x16bf16 (k = 4*(l>>4)+j). PV consumes P straight from regs:
//   o[m] = mfma16(pa[n], vb[m][n], o[m]),  vb[m][n] = V^T[16m+lr][k0+16n+4g..+3]
// D layout (row=q=4g+j, col=d=16m+lr) identical to the r7/r8-validated PV.
// -> the Pl LDS round-trip + one lgkmcnt(0) fence per iteration are GONE.
// Rt2 (Er skew window) double-buffered: remaining single fence is sufficient
// (RAW via fence; WAR separated by next iter's fence + disjoint buffers).
// __launch_bounds__(64,3): budget ~170 unified regs; single K buffer (no
// ping-pong) keeps arch+acc ~160 -> no spill (r8 lesson: never force below
// the kernel's true register need).
// ---------------------------------------------------------------------------
__global__ __launch_bounds__(64, 3) void attn_kernel(
    const unsigned short* __restrict__ Qb, const unsigned short* __restrict__ Kb,
    const unsigned short* __restrict__ Vt, const unsigned short* __restrict__ Erb,
    float* __restrict__ out)
{
    __shared__ __align__(16) float Rt2[2][80][18];

    const int lane = threadIdx.x & 63;

    const int i0    = blockIdx.x;
    const int xcd   = i0 & 7;            // XCD pin: bh in {4*xcd..4*xcd+3}
    const int b2    = (i0 >> 3) & 3;
    const int strip = (i0 >> 5) & 3;
    const int qt    = 31 - (i0 >> 7);    // heavy first
    const int bh    = (xcd << 2) | b2;

    const int lr = lane & 15;
    const int g  = lane >> 4;
    const int lk = g * 8;

    const unsigned short* __restrict__ Qrow = Qb + (size_t)bh * 2048 * 64;
    const unsigned short* __restrict__ Krow = Kb + (size_t)bh * 2048 * 64;
    const unsigned short* __restrict__ Vrow = Vt + (size_t)bh * 64 * 2048;

    const float SCL = 0.125f * 1.44269504089f;  // (1/sqrt(64)) * log2(e)
    const int bb = bh >> 4;
    const int h  = bh & 15;
    const int q0w = qt * 64 + strip * 16;

    bf16x8 aq[2];
    aq[0] = *(const bf16x8*)&Qrow[(size_t)(q0w + lr) * 64 + 0  + lk];
    aq[1] = *(const bf16x8*)&Qrow[(size_t)(q0w + lr) * 64 + 32 + lk];

    f32x4 o[4];
#pragma unroll
    for (int m = 0; m < 4; m++) o[m] = (f32x4){0.f, 0.f, 0.f, 0.f};
    float mrow = -1e30f, lsumP = 0.f;    // per-lane partial row sum

#pragma unroll 1
    for (int kt = 0; kt <= qt; ++kt) {
        const int k0 = kt * 64;
        const int rbase = 2047 + k0 - q0w - 15;   // >= 0 always
        float* __restrict__ Rb = &Rt2[kt & 1][0][0];

        // ---- K loads (single buffer; TLP hides latency at 3 waves/SIMD) ----
        bf16x8 kb[2][4];
#pragma unroll
        for (int kk = 0; kk < 2; kk++)
#pragma unroll
            for (int n = 0; n < 4; n++)
                kb[kk][n] = *(const bf16x8*)&Krow[(size_t)(k0 + n * 16 + lr) * 64 + kk * 32 + lk];

        // ---- V loads: B-fragments for K=16 PV (8B each, 16 total) ----
        bf16x4 vb[4][4];
#pragma unroll
        for (int m = 0; m < 4; m++)
#pragma unroll
            for (int n = 0; n < 4; n++)
                vb[m][n] = *(const bf16x4*)&Vrow[(size_t)(16 * m + lr) * 2048 + k0 + 16 * n + 4 * g];

        // ---- S^T = K·Q^T and R^T = Er·Q^T ----
        f32x4 s[4], r[5];
#pragma unroll
        for (int n = 0; n < 4; n++) s[n] = (f32x4){0.f, 0.f, 0.f, 0.f};
#pragma unroll
        for (int n = 0; n < 5; n++) r[n] = (f32x4){0.f, 0.f, 0.f, 0.f};
#pragma unroll
        for (int kk = 0; kk < 2; kk++) {
            bf16x8 be[5];
#pragma unroll
            for (int n = 0; n < 5; n++) {
                int rr = rbase + n * 16 + lr;
                rr = rr > 2047 ? 2047 : rr;
                be[n] = *(const bf16x8*)&Erb[(size_t)rr * 64 + kk * 32 + lk];
            }
#pragma unroll
            for (int n = 0; n < 4; n++)
                s[n] = __builtin_amdgcn_mfma_f32_16x16x32_bf16(kb[kk][n], aq[kk], s[n], 0, 0, 0);
#pragma unroll
            for (int n = 0; n < 5; n++)
                r[n] = __builtin_amdgcn_mfma_f32_16x16x32_bf16(be[n], aq[kk], r[n], 0, 0, 0);
        }

        // ---- stash QEr window (double-buffered; same-column shift) ----
#pragma unroll
        for (int n = 0; n < 5; n++)
#pragma unroll
            for (int j = 0; j < 4; j++)
                Rb[(n * 16 + g * 4 + j) * 18 + lr] = r[n][j];

        __syncthreads();   // single fence per iteration (RAW on Rb)

        // ---- combine + causal mask (in-lane) ----
        float pmax = -1e30f;
#pragma unroll
        for (int n = 0; n < 4; n++) {
#pragma unroll
            for (int j = 0; j < 4; j++) {
                int w  = n * 16 + g * 4 + j + 15 - lr;     // window pos
                float sc = (s[n][j] + Rb[w * 18 + lr]) * SCL;
                if (k0 + n * 16 + g * 4 + j > q0w + lr) sc = -1e30f;
                s[n][j] = sc;
                pmax = fmaxf(pmax, sc);
            }
        }

        // ---- T13: reduce + rescale only when the row max grows ----
        if (__any(pmax > mrow + 4.0f)) {
            pmax = fmaxf(pmax, __shfl_xor(pmax, 16));
            pmax = fmaxf(pmax, __shfl_xor(pmax, 32));
            float mn   = fmaxf(mrow, pmax);
            float corr = exp2f(mrow - mn);
            mrow = mn;
            lsumP *= corr;
#pragma unroll
            for (int j = 0; j < 4; j++) {
                float cj = __shfl(corr, g * 4 + j);
#pragma unroll
                for (int m = 0; m < 4; m++) o[m][j] *= cj;
            }
        }

        // ---- exp + pack P into A-fragments (registers, no LDS) ----
        float rs = 0.f;
        bf16x4 pa[4];
#pragma unroll
        for (int n = 0; n < 4; n++) {
#pragma unroll
            for (int j = 0; j < 4; j++) {
                float pv = exp2f(s[n][j] - mrow);
                rs += pv;
                pa[n][j] = (short)f2bf(pv);
            }
        }
        lsumP += rs;

        // ---- P @ V : 16x16x16 MFMAs, P from registers ----
#pragma unroll
        for (int m = 0; m < 4; m++)
#pragma unroll
            for (int n = 0; n < 4; n++)
                o[m] = __builtin_amdgcn_mfma_f32_16x16x16bf16_1k(pa[n], vb[m][n], o[m], 0, 0, 0);
    }

    // ---- epilogue: reduce partial lsum over g-lanes, store f32 ----
    float ls = lsumP;
    ls += __shfl_xor(ls, 16);
    ls += __shfl_xor(ls, 32);
    float linv = 1.0f / ls;              // full row-lr sum
#pragma unroll
    for (int j = 0; j < 4; j++) {
        float lj = __shfl(linv, g * 4 + j);
#pragma unroll
        for (int m = 0; m < 4; m++) {
            int row = q0w + g * 4 + j;
            int col = h * 64 + 16 * m + lr;
            out[((size_t)bb * 2048 + row) * 1024 + col] = o[m][j] * lj;
        }
    }
}

// ---------------------------------------------------------------------------
extern "C" void kernel_launch(void* const* d_in, const int* in_sizes, int n_in,
                              void* d_out, int out_size, void* d_ws, size_t ws_size,
                              hipStream_t stream)
{
    const float* x  = (const float*)d_in[0];
    const float* Wq = (const float*)d_in[1];
    const float* Wk = (const float*)d_in[2];
    const float* Wv = (const float*)d_in[3];
    const float* Er = (const float*)d_in[4];
    float* out = (float*)d_out;   // f32 output (reference returns jnp.float32)

    char* ws = (char*)d_ws;
    const size_t MB = 1024 * 1024;
    unsigned short* Qb  = (unsigned short*)(ws);            // 8 MB
    unsigned short* Kb  = (unsigned short*)(ws + 8  * MB);  // 8 MB
    unsigned short* Vt  = (unsigned short*)(ws + 16 * MB);  // 8 MB
    unsigned short* Erb = (unsigned short*)(ws + 24 * MB);  // 256 KB
    unsigned short* xb  = (unsigned short*)(ws + 25 * MB);  // 8 MB
    unsigned short* wb  = (unsigned short*)(ws + 33 * MB);  // 6 MB  (total 39 MB)

    if (ws_size >= (size_t)39 * MB) {
        cvt_bf16<<<dim3(1024), dim3(256), 0, stream>>>(x, Wq, Wk, Wv, Er, xb, wb, Erb);
        proj_kernel_bf<<<dim3(32, 24), dim3(256), 0, stream>>>(xb, wb, Qb, Kb, Vt);
    } else {
        cvt_er<<<dim3(512), dim3(256), 0, stream>>>(Er, Erb, 2048 * 64);
        proj_kernel_f32<<<dim3(32, 24), dim3(256), 0, stream>>>(x, Wq, Wk, Wv, Qb, Kb, Vt);
    }
    attn_kernel<<<dim3(4096), dim3(64), 0, stream>>>(Qb, Kb, Vt, Erb, out);
}

// Round 10
// 370.305 us; speedup vs baseline: 1.0890x; 1.0081x over previous
//
#include <hip/hip_runtime.h>
#include <hip/hip_bf16.h>
#include <stdint.h>

// Problem constants
#define S_LEN 2048
#define EMB   1024
#define NH    16
#define DH    64
#define BATCH 2

typedef short bf16x8 __attribute__((ext_vector_type(8)));
typedef short bf16x4 __attribute__((ext_vector_type(4)));
typedef float f32x4  __attribute__((ext_vector_type(4)));

__device__ __forceinline__ unsigned short f2bf(float f) {
    union { float f; unsigned int u; } v; v.f = f;
    unsigned int r = v.u + 0x7FFFu + ((v.u >> 16) & 1u);
    return (unsigned short)(r >> 16);
}

__device__ __forceinline__ bf16x8 load8f_to_bf(const float* __restrict__ p) {
    const float4* p4 = (const float4*)p;
    float4 x0 = p4[0];
    float4 x1 = p4[1];
    bf16x8 r;
    r[0] = (short)f2bf(x0.x); r[1] = (short)f2bf(x0.y);
    r[2] = (short)f2bf(x0.z); r[3] = (short)f2bf(x0.w);
    r[4] = (short)f2bf(x1.x); r[5] = (short)f2bf(x1.y);
    r[6] = (short)f2bf(x1.z); r[7] = (short)f2bf(x1.w);
    return r;
}

// ---------------------------------------------------------------------------
// Kernel 0: vectorized f32 -> bf16 conversion of x, Wq, Wk, Wv, Er.
// ---------------------------------------------------------------------------
__global__ __launch_bounds__(256) void cvt_bf16(
    const float* __restrict__ x,  const float* __restrict__ wq,
    const float* __restrict__ wk, const float* __restrict__ wv,
    const float* __restrict__ er,
    unsigned short* __restrict__ xb, unsigned short* __restrict__ wb,
    unsigned short* __restrict__ erb)
{
    const int NX = 4194304 / 8, NW = 1048576 / 8, NE = 131072 / 8;
    const int total = NX + 3 * NW + NE;
    for (int i8 = blockIdx.x * 256 + threadIdx.x; i8 < total; i8 += gridDim.x * 256) {
        const float* src; unsigned short* dst; int off;
        if      (i8 < NX)          { src = x;  dst = xb;            off = i8; }
        else if (i8 < NX + NW)     { src = wq; dst = wb;            off = i8 - NX; }
        else if (i8 < NX + 2 * NW) { src = wk; dst = wb + 1048576;  off = i8 - NX - NW; }
        else if (i8 < NX + 3 * NW) { src = wv; dst = wb + 2097152;  off = i8 - NX - 2 * NW; }
        else                       { src = er; dst = erb;           off = i8 - NX - 3 * NW; }
        ((bf16x8*)dst)[off] = load8f_to_bf(src + (size_t)off * 8);
    }
}

// ---------------------------------------------------------------------------
// Kernel 1 (fast path): QKV projection from pre-converted bf16 inputs.
// ---------------------------------------------------------------------------
__global__ __launch_bounds__(256) void proj_kernel_bf(
    const unsigned short* __restrict__ xb, const unsigned short* __restrict__ wb,
    unsigned short* __restrict__ Qb, unsigned short* __restrict__ Kb,
    unsigned short* __restrict__ Vt)
{
    const int tid  = threadIdx.x;
    const int lane = tid & 63;
    const int w    = tid >> 6;
    const int wr   = w >> 1;
    const int wc   = w & 1;
    const int m0   = blockIdx.x * 128 + wr * 64;
    const int c0   = blockIdx.y * 128 + wc * 64;
    const int wsel = c0 >> 10;
    const int f0   = c0 & 1023;
    const unsigned short* __restrict__ W = wb + (size_t)wsel * 1048576;

    const int lr = lane & 15;
    const int lk = (lane >> 4) * 8;

    f32x4 acc[4][4];
#pragma unroll
    for (int i = 0; i < 4; i++)
#pragma unroll
        for (int n = 0; n < 4; n++) acc[i][n] = (f32x4){0.f, 0.f, 0.f, 0.f};

    for (int k0 = 0; k0 < 1024; k0 += 32) {
        bf16x8 a[4], b[4];
#pragma unroll
        for (int i = 0; i < 4; i++)
            a[i] = *(const bf16x8*)&xb[(size_t)(m0 + i * 16 + lr) * 1024 + k0 + lk];
#pragma unroll
        for (int n = 0; n < 4; n++)
            b[n] = *(const bf16x8*)&W[(size_t)(f0 + n * 16 + lr) * 1024 + k0 + lk];
#pragma unroll
        for (int i = 0; i < 4; i++)
#pragma unroll
            for (int n = 0; n < 4; n++)
                acc[i][n] = __builtin_amdgcn_mfma_f32_16x16x32_bf16(a[i], b[n], acc[i][n], 0, 0, 0);
    }

    const int g = lane >> 4;
#pragma unroll
    for (int i = 0; i < 4; i++) {
#pragma unroll
        for (int n = 0; n < 4; n++) {
#pragma unroll
            for (int j = 0; j < 4; j++) {
                int row_m = m0 + i * 16 + g * 4 + j;
                int c     = c0 + n * 16 + lr;
                int f     = c & 1023;
                int h     = f >> 6;
                int dd    = f & 63;
                int bb    = row_m >> 11;
                int s     = row_m & 2047;
                int bh    = bb * 16 + h;
                unsigned short bv = f2bf(acc[i][n][j]);
                if (wsel == 0)      Qb[((size_t)bh * 2048 + s) * 64 + dd] = bv;
                else if (wsel == 1) Kb[((size_t)bh * 2048 + s) * 64 + dd] = bv;
                else                Vt[((size_t)bh * 64 + dd) * 2048 + s] = bv;
            }
        }
    }
}

// ---------------------------------------------------------------------------
// Kernel 1 (fallback): f32 inputs with in-loop convert.
// ---------------------------------------------------------------------------
__global__ __launch_bounds__(256) void proj_kernel_f32(
    const float* __restrict__ x,
    const float* __restrict__ Wq, const float* __restrict__ Wk,
    const float* __restrict__ Wv,
    unsigned short* __restrict__ Qb, unsigned short* __restrict__ Kb,
    unsigned short* __restrict__ Vt)
{
    const int tid  = threadIdx.x;
    const int lane = tid & 63;
    const int w    = tid >> 6;
    const int wr   = w >> 1;
    const int wc   = w & 1;
    const int m0   = blockIdx.x * 128 + wr * 64;
    const int c0   = blockIdx.y * 128 + wc * 64;
    const int wsel = c0 >> 10;
    const int f0   = c0 & 1023;
    const float* __restrict__ W = (wsel == 0) ? Wq : (wsel == 1) ? Wk : Wv;

    const int lr = lane & 15;
    const int lk = (lane >> 4) * 8;

    f32x4 acc[4][4];
#pragma unroll
    for (int i = 0; i < 4; i++)
#pragma unroll
        for (int n = 0; n < 4; n++) acc[i][n] = (f32x4){0.f, 0.f, 0.f, 0.f};

    for (int k0 = 0; k0 < 1024; k0 += 32) {
        bf16x8 a[4], b[4];
#pragma unroll
        for (int i = 0; i < 4; i++)
            a[i] = load8f_to_bf(&x[(size_t)(m0 + i * 16 + lr) * 1024 + k0 + lk]);
#pragma unroll
        for (int n = 0; n < 4; n++)
            b[n] = load8f_to_bf(&W[(size_t)(f0 + n * 16 + lr) * 1024 + k0 + lk]);
#pragma unroll
        for (int i = 0; i < 4; i++)
#pragma unroll
            for (int n = 0; n < 4; n++)
                acc[i][n] = __builtin_amdgcn_mfma_f32_16x16x32_bf16(a[i], b[n], acc[i][n], 0, 0, 0);
    }

    const int g = lane >> 4;
#pragma unroll
    for (int i = 0; i < 4; i++) {
#pragma unroll
        for (int n = 0; n < 4; n++) {
#pragma unroll
            for (int j = 0; j < 4; j++) {
                int row_m = m0 + i * 16 + g * 4 + j;
                int c     = c0 + n * 16 + lr;
                int f     = c & 1023;
                int h     = f >> 6;
                int dd    = f & 63;
                int bb    = row_m >> 11;
                int s     = row_m & 2047;
                int bh    = bb * 16 + h;
                unsigned short bv = f2bf(acc[i][n][j]);
                if (wsel == 0)      Qb[((size_t)bh * 2048 + s) * 64 + dd] = bv;
                else if (wsel == 1) Kb[((size_t)bh * 2048 + s) * 64 + dd] = bv;
                else                Vt[((size_t)bh * 64 + dd) * 2048 + s] = bv;
            }
        }
    }
}

__global__ void cvt_er(const float* __restrict__ Er, unsigned short* __restrict__ Erb, int n)
{
    int i = blockIdx.x * 256 + threadIdx.x;
    if (i < n) Erb[i] = f2bf(Er[i]);
}

// ---------------------------------------------------------------------------
// Kernel 2: flash attention, swapped-operand, register-resident P,
// K+V double-buffered prefetch (r7 structure + r9 PV path).
// r9 lesson: dropping the prefetch exposed per-iteration global latency
// (attn 202->269 despite 30% occupancy). r8 lesson: never force launch
// bounds below the true register need. So: (64,2), both K and V ping-pong.
// ---------------------------------------------------------------------------
__global__ __launch_bounds__(64, 2) void attn_kernel(
    const unsigned short* __restrict__ Qb, const unsigned short* __restrict__ Kb,
    const unsigned short* __restrict__ Vt, const unsigned short* __restrict__ Erb,
    float* __restrict__ out)
{
    __shared__ __align__(16) float Rt2[2][80][18];

    const int lane = threadIdx.x & 63;

    const int i0    = blockIdx.x;
    const int xcd   = i0 & 7;            // XCD pin: bh in {4*xcd..4*xcd+3}
    const int b2    = (i0 >> 3) & 3;
    const int strip = (i0 >> 5) & 3;
    const int qt    = 31 - (i0 >> 7);    // heavy first
    const int bh    = (xcd << 2) | b2;

    const int lr = lane & 15;
    const int g  = lane >> 4;
    const int lk = g * 8;

    const unsigned short* __restrict__ Qrow = Qb + (size_t)bh * 2048 * 64;
    const unsigned short* __restrict__ Krow = Kb + (size_t)bh * 2048 * 64;
    const unsigned short* __restrict__ Vrow = Vt + (size_t)bh * 64 * 2048;

    const float SCL = 0.125f * 1.44269504089f;  // (1/sqrt(64)) * log2(e)
    const int bb = bh >> 4;
    const int h  = bh & 15;
    const int q0w = qt * 64 + strip * 16;

    bf16x8 aq[2];
    aq[0] = *(const bf16x8*)&Qrow[(size_t)(q0w + lr) * 64 + 0  + lk];
    aq[1] = *(const bf16x8*)&Qrow[(size_t)(q0w + lr) * 64 + 32 + lk];

    f32x4 o[4];
#pragma unroll
    for (int m = 0; m < 4; m++) o[m] = (f32x4){0.f, 0.f, 0.f, 0.f};
    float mrow = -1e30f, lsumP = 0.f;    // per-lane partial row sum

    // ---- prefetch helpers: K (8x16B) + V (16x8B B-fragments) ----
    auto loadKV = [&](bf16x8 (&kb)[2][4], bf16x4 (&vb)[4][4], int kt) {
        const int k0 = kt * 64;
#pragma unroll
        for (int kk = 0; kk < 2; kk++)
#pragma unroll
            for (int n = 0; n < 4; n++)
                kb[kk][n] = *(const bf16x8*)&Krow[(size_t)(k0 + n * 16 + lr) * 64 + kk * 32 + lk];
#pragma unroll
        for (int m = 0; m < 4; m++)
#pragma unroll
            for (int n = 0; n < 4; n++)
                vb[m][n] = *(const bf16x4*)&Vrow[(size_t)(16 * m + lr) * 2048 + k0 + 16 * n + 4 * g];
    };

    auto body = [&](const bf16x8 (&kb)[2][4], const bf16x4 (&vb)[4][4], int kt) {
        const int k0 = kt * 64;
        const int rbase = 2047 + k0 - q0w - 15;   // >= 0 always
        float* __restrict__ Rb = &Rt2[kt & 1][0][0];

        // ---- S^T = K·Q^T and R^T = Er·Q^T ----
        f32x4 s[4], r[5];
#pragma unroll
        for (int n = 0; n < 4; n++) s[n] = (f32x4){0.f, 0.f, 0.f, 0.f};
#pragma unroll
        for (int n = 0; n < 5; n++) r[n] = (f32x4){0.f, 0.f, 0.f, 0.f};
#pragma unroll
        for (int kk = 0; kk < 2; kk++) {
            bf16x8 be[5];
#pragma unroll
            for (int n = 0; n < 5; n++) {
                int rr = rbase + n * 16 + lr;
                rr = rr > 2047 ? 2047 : rr;
                be[n] = *(const bf16x8*)&Erb[(size_t)rr * 64 + kk * 32 + lk];
            }
#pragma unroll
            for (int n = 0; n < 4; n++)
                s[n] = __builtin_amdgcn_mfma_f32_16x16x32_bf16(kb[kk][n], aq[kk], s[n], 0, 0, 0);
#pragma unroll
            for (int n = 0; n < 5; n++)
                r[n] = __builtin_amdgcn_mfma_f32_16x16x32_bf16(be[n], aq[kk], r[n], 0, 0, 0);
        }

        // ---- stash QEr window (double-buffered; same-column shift) ----
#pragma unroll
        for (int n = 0; n < 5; n++)
#pragma unroll
            for (int j = 0; j < 4; j++)
                Rb[(n * 16 + g * 4 + j) * 18 + lr] = r[n][j];

        __syncthreads();   // single fence per iteration (RAW on Rb)

        // ---- combine + causal mask (in-lane) ----
        float pmax = -1e30f;
#pragma unroll
        for (int n = 0; n < 4; n++) {
#pragma unroll
            for (int j = 0; j < 4; j++) {
                int w  = n * 16 + g * 4 + j + 15 - lr;     // window pos
                float sc = (s[n][j] + Rb[w * 18 + lr]) * SCL;
                if (k0 + n * 16 + g * 4 + j > q0w + lr) sc = -1e30f;
                s[n][j] = sc;
                pmax = fmaxf(pmax, sc);
            }
        }

        // ---- T13: reduce + rescale only when the row max grows ----
        if (__any(pmax > mrow + 4.0f)) {
            pmax = fmaxf(pmax, __shfl_xor(pmax, 16));
            pmax = fmaxf(pmax, __shfl_xor(pmax, 32));
            float mn   = fmaxf(mrow, pmax);
            float corr = exp2f(mrow - mn);
            mrow = mn;
            lsumP *= corr;
#pragma unroll
            for (int j = 0; j < 4; j++) {
                float cj = __shfl(corr, g * 4 + j);
#pragma unroll
                for (int m = 0; m < 4; m++) o[m][j] *= cj;
            }
        }

        // ---- exp + pack P into A-fragments (registers, no LDS) ----
        float rs = 0.f;
        bf16x4 pa[4];
#pragma unroll
        for (int n = 0; n < 4; n++) {
#pragma unroll
            for (int j = 0; j < 4; j++) {
                float pv = exp2f(s[n][j] - mrow);
                rs += pv;
                pa[n][j] = (short)f2bf(pv);
            }
        }
        lsumP += rs;

        // ---- P @ V : 16x16x16 MFMAs, P from registers ----
#pragma unroll
        for (int m = 0; m < 4; m++)
#pragma unroll
            for (int n = 0; n < 4; n++)
                o[m] = __builtin_amdgcn_mfma_f32_16x16x16bf16_1k(pa[n], vb[m][n], o[m], 0, 0, 0);
    };

    // ---- K+V register double-buffer, ping-pong with static buffers ----
    bf16x8 kA[2][4], kB[2][4];
    bf16x4 vA[4][4], vB[4][4];
    loadKV(kA, vA, 0);
    int kt = 0;
    while (true) {
        if (kt + 1 <= qt) loadKV(kB, vB, kt + 1);
        body(kA, vA, kt);
        kt++;
        if (kt > qt) break;
        if (kt + 1 <= qt) loadKV(kA, vA, kt + 1);
        body(kB, vB, kt);
        kt++;
        if (kt > qt) break;
    }

    // ---- epilogue: reduce partial lsum over g-lanes, store f32 ----
    float ls = lsumP;
    ls += __shfl_xor(ls, 16);
    ls += __shfl_xor(ls, 32);
    float linv = 1.0f / ls;              // full row-lr sum
#pragma unroll
    for (int j = 0; j < 4; j++) {
        float lj = __shfl(linv, g * 4 + j);
#pragma unroll
        for (int m = 0; m < 4; m++) {
            int row = q0w + g * 4 + j;
            int col = h * 64 + 16 * m + lr;
            out[((size_t)bb * 2048 + row) * 1024 + col] = o[m][j] * lj;
        }
    }
}

// ---------------------------------------------------------------------------
extern "C" void kernel_launch(void* const* d_in, const int* in_sizes, int n_in,
                              void* d_out, int out_size, void* d_ws, size_t ws_size,
                              hipStream_t stream)
{
    const float* x  = (const float*)d_in[0];
    const float* Wq = (const float*)d_in[1];
    const float* Wk = (const float*)d_in[2];
    const float* Wv = (const float*)d_in[3];
    const float* Er = (const float*)d_in[4];
    float* out = (float*)d_out;   // f32 output (reference returns jnp.float32)

    char* ws = (char*)d_ws;
    const size_t MB = 1024 * 1024;
    unsigned short* Qb  = (unsigned short*)(ws);            // 8 MB
    unsigned short* Kb  = (unsigned short*)(ws + 8  * MB);  // 8 MB
    unsigned short* Vt  = (unsigned short*)(ws + 16 * MB);  // 8 MB
    unsigned short* Erb = (unsigned short*)(ws + 24 * MB);  // 256 KB
    unsigned short* xb  = (unsigned short*)(ws + 25 * MB);  // 8 MB
    unsigned short* wb  = (unsigned short*)(ws + 33 * MB);  // 6 MB  (total 39 MB)

    if (ws_size >= (size_t)39 * MB) {
        cvt_bf16<<<dim3(1024), dim3(256), 0, stream>>>(x, Wq, Wk, Wv, Er, xb, wb, Erb);
        proj_kernel_bf<<<dim3(32, 24), dim3(256), 0, stream>>>(xb, wb, Qb, Kb, Vt);
    } else {
        cvt_er<<<dim3(512), dim3(256), 0, stream>>>(Er, Erb, 2048 * 64);
        proj_kernel_f32<<<dim3(32, 24), dim3(256), 0, stream>>>(x, Wq, Wk, Wv, Qb, Kb, Vt);
    }
    attn_kernel<<<dim3(4096), dim3(64), 0, stream>>>(Qb, Kb, Vt, Erb, out);
}

// Round 11
// 299.826 us; speedup vs baseline: 1.3450x; 1.2351x over previous
//
#include <hip/hip_runtime.h>
#include <hip/hip_bf16.h>
#include <stdint.h>

// Problem constants
#define S_LEN 2048
#define EMB   1024
#define NH    16
#define DH    64
#define BATCH 2

typedef short bf16x8 __attribute__((ext_vector_type(8)));
typedef short bf16x4 __attribute__((ext_vector_type(4)));
typedef float f32x4  __attribute__((ext_vector_type(4)));

__device__ __forceinline__ unsigned short f2bf(float f) {
    union { float f; unsigned int u; } v; v.f = f;
    unsigned int r = v.u + 0x7FFFu + ((v.u >> 16) & 1u);
    return (unsigned short)(r >> 16);
}

__device__ __forceinline__ bf16x8 load8f_to_bf(const float* __restrict__ p) {
    const float4* p4 = (const float4*)p;
    float4 x0 = p4[0];
    float4 x1 = p4[1];
    bf16x8 r;
    r[0] = (short)f2bf(x0.x); r[1] = (short)f2bf(x0.y);
    r[2] = (short)f2bf(x0.z); r[3] = (short)f2bf(x0.w);
    r[4] = (short)f2bf(x1.x); r[5] = (short)f2bf(x1.y);
    r[6] = (short)f2bf(x1.z); r[7] = (short)f2bf(x1.w);
    return r;
}

// ---------------------------------------------------------------------------
// Kernel 0: vectorized f32 -> bf16 conversion of x, Wq, Wk, Wv, Er.
// ---------------------------------------------------------------------------
__global__ __launch_bounds__(256) void cvt_bf16(
    const float* __restrict__ x,  const float* __restrict__ wq,
    const float* __restrict__ wk, const float* __restrict__ wv,
    const float* __restrict__ er,
    unsigned short* __restrict__ xb, unsigned short* __restrict__ wb,
    unsigned short* __restrict__ erb)
{
    const int NX = 4194304 / 8, NW = 1048576 / 8, NE = 131072 / 8;
    const int total = NX + 3 * NW + NE;
    for (int i8 = blockIdx.x * 256 + threadIdx.x; i8 < total; i8 += gridDim.x * 256) {
        const float* src; unsigned short* dst; int off;
        if      (i8 < NX)          { src = x;  dst = xb;            off = i8; }
        else if (i8 < NX + NW)     { src = wq; dst = wb;            off = i8 - NX; }
        else if (i8 < NX + 2 * NW) { src = wk; dst = wb + 1048576;  off = i8 - NX - NW; }
        else if (i8 < NX + 3 * NW) { src = wv; dst = wb + 2097152;  off = i8 - NX - 2 * NW; }
        else                       { src = er; dst = erb;           off = i8 - NX - 3 * NW; }
        ((bf16x8*)dst)[off] = load8f_to_bf(src + (size_t)off * 8);
    }
}

// ---------------------------------------------------------------------------
// Kernel 1 (fast path): QKV projection from pre-converted bf16 inputs.
// ---------------------------------------------------------------------------
__global__ __launch_bounds__(256) void proj_kernel_bf(
    const unsigned short* __restrict__ xb, const unsigned short* __restrict__ wb,
    unsigned short* __restrict__ Qb, unsigned short* __restrict__ Kb,
    unsigned short* __restrict__ Vt)
{
    const int tid  = threadIdx.x;
    const int lane = tid & 63;
    const int w    = tid >> 6;
    const int wr   = w >> 1;
    const int wc   = w & 1;
    const int m0   = blockIdx.x * 128 + wr * 64;
    const int c0   = blockIdx.y * 128 + wc * 64;
    const int wsel = c0 >> 10;
    const int f0   = c0 & 1023;
    const unsigned short* __restrict__ W = wb + (size_t)wsel * 1048576;

    const int lr = lane & 15;
    const int lk = (lane >> 4) * 8;

    f32x4 acc[4][4];
#pragma unroll
    for (int i = 0; i < 4; i++)
#pragma unroll
        for (int n = 0; n < 4; n++) acc[i][n] = (f32x4){0.f, 0.f, 0.f, 0.f};

    for (int k0 = 0; k0 < 1024; k0 += 32) {
        bf16x8 a[4], b[4];
#pragma unroll
        for (int i = 0; i < 4; i++)
            a[i] = *(const bf16x8*)&xb[(size_t)(m0 + i * 16 + lr) * 1024 + k0 + lk];
#pragma unroll
        for (int n = 0; n < 4; n++)
            b[n] = *(const bf16x8*)&W[(size_t)(f0 + n * 16 + lr) * 1024 + k0 + lk];
#pragma unroll
        for (int i = 0; i < 4; i++)
#pragma unroll
            for (int n = 0; n < 4; n++)
                acc[i][n] = __builtin_amdgcn_mfma_f32_16x16x32_bf16(a[i], b[n], acc[i][n], 0, 0, 0);
    }

    const int g = lane >> 4;
#pragma unroll
    for (int i = 0; i < 4; i++) {
#pragma unroll
        for (int n = 0; n < 4; n++) {
#pragma unroll
            for (int j = 0; j < 4; j++) {
                int row_m = m0 + i * 16 + g * 4 + j;
                int c     = c0 + n * 16 + lr;
                int f     = c & 1023;
                int h     = f >> 6;
                int dd    = f & 63;
                int bb    = row_m >> 11;
                int s     = row_m & 2047;
                int bh    = bb * 16 + h;
                unsigned short bv = f2bf(acc[i][n][j]);
                if (wsel == 0)      Qb[((size_t)bh * 2048 + s) * 64 + dd] = bv;
                else if (wsel == 1) Kb[((size_t)bh * 2048 + s) * 64 + dd] = bv;
                else                Vt[((size_t)bh * 64 + dd) * 2048 + s] = bv;
            }
        }
    }
}

// ---------------------------------------------------------------------------
// Kernel 1 (fallback): f32 inputs with in-loop convert.
// ---------------------------------------------------------------------------
__global__ __launch_bounds__(256) void proj_kernel_f32(
    const float* __restrict__ x,
    const float* __restrict__ Wq, const float* __restrict__ Wk,
    const float* __restrict__ Wv,
    unsigned short* __restrict__ Qb, unsigned short* __restrict__ Kb,
    unsigned short* __restrict__ Vt)
{
    const int tid  = threadIdx.x;
    const int lane = tid & 63;
    const int w    = tid >> 6;
    const int wr   = w >> 1;
    const int wc   = w & 1;
    const int m0   = blockIdx.x * 128 + wr * 64;
    const int c0   = blockIdx.y * 128 + wc * 64;
    const int wsel = c0 >> 10;
    const int f0   = c0 & 1023;
    const float* __restrict__ W = (wsel == 0) ? Wq : (wsel == 1) ? Wk : Wv;

    const int lr = lane & 15;
    const int lk = (lane >> 4) * 8;

    f32x4 acc[4][4];
#pragma unroll
    for (int i = 0; i < 4; i++)
#pragma unroll
        for (int n = 0; n < 4; n++) acc[i][n] = (f32x4){0.f, 0.f, 0.f, 0.f};

    for (int k0 = 0; k0 < 1024; k0 += 32) {
        bf16x8 a[4], b[4];
#pragma unroll
        for (int i = 0; i < 4; i++)
            a[i] = load8f_to_bf(&x[(size_t)(m0 + i * 16 + lr) * 1024 + k0 + lk]);
#pragma unroll
        for (int n = 0; n < 4; n++)
            b[n] = load8f_to_bf(&W[(size_t)(f0 + n * 16 + lr) * 1024 + k0 + lk]);
#pragma unroll
        for (int i = 0; i < 4; i++)
#pragma unroll
            for (int n = 0; n < 4; n++)
                acc[i][n] = __builtin_amdgcn_mfma_f32_16x16x32_bf16(a[i], b[n], acc[i][n], 0, 0, 0);
    }

    const int g = lane >> 4;
#pragma unroll
    for (int i = 0; i < 4; i++) {
#pragma unroll
        for (int n = 0; n < 4; n++) {
#pragma unroll
            for (int j = 0; j < 4; j++) {
                int row_m = m0 + i * 16 + g * 4 + j;
                int c     = c0 + n * 16 + lr;
                int f     = c & 1023;
                int h     = f >> 6;
                int dd    = f & 63;
                int bb    = row_m >> 11;
                int s     = row_m & 2047;
                int bh    = bb * 16 + h;
                unsigned short bv = f2bf(acc[i][n][j]);
                if (wsel == 0)      Qb[((size_t)bh * 2048 + s) * 64 + dd] = bv;
                else if (wsel == 1) Kb[((size_t)bh * 2048 + s) * 64 + dd] = bv;
                else                Vt[((size_t)bh * 64 + dd) * 2048 + s] = bv;
            }
        }
    }
}

__global__ void cvt_er(const float* __restrict__ Er, unsigned short* __restrict__ Erb, int n)
{
    int i = blockIdx.x * 256 + threadIdx.x;
    if (i < n) Erb[i] = f2bf(Er[i]);
}

// ---------------------------------------------------------------------------
// Kernel 2: flash attention, swapped-operand, 32 Q-ROWS PER WAVE (2 strips).
// K tile (8 loads) + V tile (16 loads) shared by both strips; Er windows of
// the strips overlap by 64 rows -> merged 96-row window, 12 loads (vs 20).
// VMEM issue order matched to consumption (vmcnt is in-order): be first
// (used by Er MFMA), vb mid-body (used at PV, ~full body of cover), K-next
// prefetch last (used next iteration).
// Strip s covers q rows [q0+16s, q0+16s+16); rbaseU = strip1's window base;
// strip1 uses be[0..4], strip0 uses be[1..5].
// Grid 2048 = (xcd:3 | b2:2 | half:1 | qt:5), heavy-first, XCD-pinned KV.
// __launch_bounds__(64,2): est ~230 unified regs -> must not spill (r8).
// ---------------------------------------------------------------------------
__global__ __launch_bounds__(64, 2) void attn_kernel(
    const unsigned short* __restrict__ Qb, const unsigned short* __restrict__ Kb,
    const unsigned short* __restrict__ Vt, const unsigned short* __restrict__ Erb,
    float* __restrict__ out)
{
    __shared__ __align__(16) float Rt2[2][80][18];

    const int lane = threadIdx.x & 63;

    const int i0    = blockIdx.x;
    const int xcd   = i0 & 7;            // XCD pin: bh in {4*xcd..4*xcd+3}
    const int b2    = (i0 >> 3) & 3;
    const int half  = (i0 >> 5) & 1;
    const int qt    = 31 - (i0 >> 6);    // heavy first
    const int bh    = (xcd << 2) | b2;

    const int lr = lane & 15;
    const int g  = lane >> 4;
    const int lk = g * 8;

    const unsigned short* __restrict__ Qrow = Qb + (size_t)bh * 2048 * 64;
    const unsigned short* __restrict__ Krow = Kb + (size_t)bh * 2048 * 64;
    const unsigned short* __restrict__ Vrow = Vt + (size_t)bh * 64 * 2048;

    const float SCL = 0.125f * 1.44269504089f;  // (1/sqrt(64)) * log2(e)
    const int bb = bh >> 4;
    const int h  = bh & 15;
    const int q0 = qt * 64 + half * 32;         // strips: q0 .. q0+31

    bf16x8 aq0[2], aq1[2];
#pragma unroll
    for (int kk = 0; kk < 2; kk++) {
        aq0[kk] = *(const bf16x8*)&Qrow[(size_t)(q0 + lr) * 64 + kk * 32 + lk];
        aq1[kk] = *(const bf16x8*)&Qrow[(size_t)(q0 + 16 + lr) * 64 + kk * 32 + lk];
    }

    f32x4 o0[4], o1[4];
#pragma unroll
    for (int m = 0; m < 4; m++) { o0[m] = (f32x4){0.f,0.f,0.f,0.f}; o1[m] = (f32x4){0.f,0.f,0.f,0.f}; }
    float mrow0 = -1e30f, mrow1 = -1e30f, lsum0 = 0.f, lsum1 = 0.f;

    auto loadK = [&](bf16x8 (&kb)[2][4], int kt) {
        const int k0 = kt * 64;
#pragma unroll
        for (int kk = 0; kk < 2; kk++)
#pragma unroll
            for (int n = 0; n < 4; n++)
                kb[kk][n] = *(const bf16x8*)&Krow[(size_t)(k0 + n * 16 + lr) * 64 + kk * 32 + lk];
    };

    auto body = [&](const bf16x8 (&kb)[2][4], bf16x8 (&kbn)[2][4], int kt) {
        const int k0 = kt * 64;
        const int rbaseU = 2047 + k0 - q0 - 31;   // strip1 base; strip0 = +16
        float* __restrict__ Rb = &Rt2[0][0][0];   // strip0 region
        float* __restrict__ Rc = &Rt2[1][0][0];   // strip1 region

        // ---- S and R for both strips (be issued first; QK covers latency) ----
        f32x4 s0[4], s1[4], r0[5], r1[5];
#pragma unroll
        for (int n = 0; n < 4; n++) { s0[n] = (f32x4){0.f,0.f,0.f,0.f}; s1[n] = (f32x4){0.f,0.f,0.f,0.f}; }
#pragma unroll
        for (int n = 0; n < 5; n++) { r0[n] = (f32x4){0.f,0.f,0.f,0.f}; r1[n] = (f32x4){0.f,0.f,0.f,0.f}; }
#pragma unroll
        for (int kk = 0; kk < 2; kk++) {
            bf16x8 be[6];
#pragma unroll
            for (int n = 0; n < 6; n++) {
                int rr = rbaseU + n * 16 + lr;
                rr = rr > 2047 ? 2047 : rr;
                be[n] = *(const bf16x8*)&Erb[(size_t)rr * 64 + kk * 32 + lk];
            }
#pragma unroll
            for (int n = 0; n < 4; n++)
                s0[n] = __builtin_amdgcn_mfma_f32_16x16x32_bf16(kb[kk][n], aq0[kk], s0[n], 0, 0, 0);
#pragma unroll
            for (int n = 0; n < 4; n++)
                s1[n] = __builtin_amdgcn_mfma_f32_16x16x32_bf16(kb[kk][n], aq1[kk], s1[n], 0, 0, 0);
#pragma unroll
            for (int n = 0; n < 5; n++)
                r0[n] = __builtin_amdgcn_mfma_f32_16x16x32_bf16(be[n + 1], aq0[kk], r0[n], 0, 0, 0);
#pragma unroll
            for (int n = 0; n < 5; n++)
                r1[n] = __builtin_amdgcn_mfma_f32_16x16x32_bf16(be[n], aq1[kk], r1[n], 0, 0, 0);
        }

        // ---- V loads (consumed at PV; whole body of latency cover) ----
        bf16x4 vb[4][4];
#pragma unroll
        for (int m = 0; m < 4; m++)
#pragma unroll
            for (int n = 0; n < 4; n++)
                vb[m][n] = *(const bf16x4*)&Vrow[(size_t)(16 * m + lr) * 2048 + k0 + 16 * n + 4 * g];

        // ---- next-tile K prefetch (consumed next iteration) ----
        if (kt + 1 <= qt) loadK(kbn, kt + 1);

        __syncthreads();   // protect previous iteration's Rt2 reads (WAR)
#pragma unroll
        for (int n = 0; n < 5; n++)
#pragma unroll
            for (int j = 0; j < 4; j++) {
                Rb[(n * 16 + g * 4 + j) * 18 + lr] = r0[n][j];
                Rc[(n * 16 + g * 4 + j) * 18 + lr] = r1[n][j];
            }
        __syncthreads();   // RAW: writes -> cross-lane reads

        // ================= strip 0 softmax =================
        {
            float pmax = -1e30f;
#pragma unroll
            for (int n = 0; n < 4; n++) {
#pragma unroll
                for (int j = 0; j < 4; j++) {
                    int w  = n * 16 + g * 4 + j + 15 - lr;
                    float sc = (s0[n][j] + Rb[w * 18 + lr]) * SCL;
                    if (k0 + n * 16 + g * 4 + j > q0 + lr) sc = -1e30f;
                    s0[n][j] = sc;
                    pmax = fmaxf(pmax, sc);
                }
            }
            if (__any(pmax > mrow0 + 4.0f)) {
                pmax = fmaxf(pmax, __shfl_xor(pmax, 16));
                pmax = fmaxf(pmax, __shfl_xor(pmax, 32));
                float mn   = fmaxf(mrow0, pmax);
                float corr = exp2f(mrow0 - mn);
                mrow0 = mn;
                lsum0 *= corr;
#pragma unroll
                for (int j = 0; j < 4; j++) {
                    float cj = __shfl(corr, g * 4 + j);
#pragma unroll
                    for (int m = 0; m < 4; m++) o0[m][j] *= cj;
                }
            }
        }
        float rs0 = 0.f;
        bf16x4 pa0[4];
#pragma unroll
        for (int n = 0; n < 4; n++)
#pragma unroll
            for (int j = 0; j < 4; j++) {
                float pv = exp2f(s0[n][j] - mrow0);
                rs0 += pv;
                pa0[n][j] = (short)f2bf(pv);
            }
        lsum0 += rs0;

        // ================= strip 1 softmax =================
        {
            float pmax = -1e30f;
#pragma unroll
            for (int n = 0; n < 4; n++) {
#pragma unroll
                for (int j = 0; j < 4; j++) {
                    int w  = n * 16 + g * 4 + j + 15 - lr;
                    float sc = (s1[n][j] + Rc[w * 18 + lr]) * SCL;
                    if (k0 + n * 16 + g * 4 + j > q0 + 16 + lr) sc = -1e30f;
                    s1[n][j] = sc;
                    pmax = fmaxf(pmax, sc);
                }
            }
            if (__any(pmax > mrow1 + 4.0f)) {
                pmax = fmaxf(pmax, __shfl_xor(pmax, 16));
                pmax = fmaxf(pmax, __shfl_xor(pmax, 32));
                float mn   = fmaxf(mrow1, pmax);
                float corr = exp2f(mrow1 - mn);
                mrow1 = mn;
                lsum1 *= corr;
#pragma unroll
                for (int j = 0; j < 4; j++) {
                    float cj = __shfl(corr, g * 4 + j);
#pragma unroll
                    for (int m = 0; m < 4; m++) o1[m][j] *= cj;
                }
            }
        }
        float rs1 = 0.f;
        bf16x4 pa1[4];
#pragma unroll
        for (int n = 0; n < 4; n++)
#pragma unroll
            for (int j = 0; j < 4; j++) {
                float pv = exp2f(s1[n][j] - mrow1);
                rs1 += pv;
                pa1[n][j] = (short)f2bf(pv);
            }
        lsum1 += rs1;

        // ---- P @ V for both strips (V shared) ----
#pragma unroll
        for (int m = 0; m < 4; m++)
#pragma unroll
            for (int n = 0; n < 4; n++) {
                o0[m] = __builtin_amdgcn_mfma_f32_16x16x16bf16_1k(pa0[n], vb[m][n], o0[m], 0, 0, 0);
                o1[m] = __builtin_amdgcn_mfma_f32_16x16x16bf16_1k(pa1[n], vb[m][n], o1[m], 0, 0, 0);
            }
    };

    // ---- K ping-pong double buffer ----
    bf16x8 kA[2][4], kB[2][4];
    loadK(kA, 0);
    int kt = 0;
    while (true) {
        body(kA, kB, kt);
        kt++;
        if (kt > qt) break;
        body(kB, kA, kt);
        kt++;
        if (kt > qt) break;
    }

    // ---- epilogue: per-strip lsum reduce over g-lanes, store f32 ----
    {
        float ls = lsum0;
        ls += __shfl_xor(ls, 16);
        ls += __shfl_xor(ls, 32);
        float linv = 1.0f / ls;
#pragma unroll
        for (int j = 0; j < 4; j++) {
            float lj = __shfl(linv, g * 4 + j);
#pragma unroll
            for (int m = 0; m < 4; m++) {
                int row = q0 + g * 4 + j;
                int col = h * 64 + 16 * m + lr;
                out[((size_t)bb * 2048 + row) * 1024 + col] = o0[m][j] * lj;
            }
        }
    }
    {
        float ls = lsum1;
        ls += __shfl_xor(ls, 16);
        ls += __shfl_xor(ls, 32);
        float linv = 1.0f / ls;
#pragma unroll
        for (int j = 0; j < 4; j++) {
            float lj = __shfl(linv, g * 4 + j);
#pragma unroll
            for (int m = 0; m < 4; m++) {
                int row = q0 + 16 + g * 4 + j;
                int col = h * 64 + 16 * m + lr;
                out[((size_t)bb * 2048 + row) * 1024 + col] = o1[m][j] * lj;
            }
        }
    }
}

// ---------------------------------------------------------------------------
extern "C" void kernel_launch(void* const* d_in, const int* in_sizes, int n_in,
                              void* d_out, int out_size, void* d_ws, size_t ws_size,
                              hipStream_t stream)
{
    const float* x  = (const float*)d_in[0];
    const float* Wq = (const float*)d_in[1];
    const float* Wk = (const float*)d_in[2];
    const float* Wv = (const float*)d_in[3];
    const float* Er = (const float*)d_in[4];
    float* out = (float*)d_out;   // f32 output (reference returns jnp.float32)

    char* ws = (char*)d_ws;
    const size_t MB = 1024 * 1024;
    unsigned short* Qb  = (unsigned short*)(ws);            // 8 MB
    unsigned short* Kb  = (unsigned short*)(ws + 8  * MB);  // 8 MB
    unsigned short* Vt  = (unsigned short*)(ws + 16 * MB);  // 8 MB
    unsigned short* Erb = (unsigned short*)(ws + 24 * MB);  // 256 KB
    unsigned short* xb  = (unsigned short*)(ws + 25 * MB);  // 8 MB
    unsigned short* wb  = (unsigned short*)(ws + 33 * MB);  // 6 MB  (total 39 MB)

    if (ws_size >= (size_t)39 * MB) {
        cvt_bf16<<<dim3(1024), dim3(256), 0, stream>>>(x, Wq, Wk, Wv, Er, xb, wb, Erb);
        proj_kernel_bf<<<dim3(32, 24), dim3(256), 0, stream>>>(xb, wb, Qb, Kb, Vt);
    } else {
        cvt_er<<<dim3(512), dim3(256), 0, stream>>>(Er, Erb, 2048 * 64);
        proj_kernel_f32<<<dim3(32, 24), dim3(256), 0, stream>>>(x, Wq, Wk, Wv, Qb, Kb, Vt);
    }
    attn_kernel<<<dim3(2048), dim3(64), 0, stream>>>(Qb, Kb, Vt, Erb, out);
}

// Round 12
// 200.339 us; speedup vs baseline: 2.0130x; 1.4966x over previous
//
#include <hip/hip_runtime.h>
#include <hip/hip_bf16.h>
#include <stdint.h>

// Problem constants
#define S_LEN 2048
#define EMB   1024
#define NH    16
#define DH    64
#define BATCH 2

typedef short bf16x8 __attribute__((ext_vector_type(8)));
typedef short bf16x4 __attribute__((ext_vector_type(4)));
typedef float f32x4  __attribute__((ext_vector_type(4)));

__device__ __forceinline__ unsigned short f2bf(float f) {
    union { float f; unsigned int u; } v; v.f = f;
    unsigned int r = v.u + 0x7FFFu + ((v.u >> 16) & 1u);
    return (unsigned short)(r >> 16);
}

__device__ __forceinline__ bf16x8 load8f_to_bf(const float* __restrict__ p) {
    const float4* p4 = (const float4*)p;
    float4 x0 = p4[0];
    float4 x1 = p4[1];
    bf16x8 r;
    r[0] = (short)f2bf(x0.x); r[1] = (short)f2bf(x0.y);
    r[2] = (short)f2bf(x0.z); r[3] = (short)f2bf(x0.w);
    r[4] = (short)f2bf(x1.x); r[5] = (short)f2bf(x1.y);
    r[6] = (short)f2bf(x1.z); r[7] = (short)f2bf(x1.w);
    return r;
}

// LDS barrier that does NOT drain vmcnt: lets T14 stage-prefetch global loads
// stay in flight across the barrier (HIP __syncthreads would emit
// s_waitcnt vmcnt(0) and serialize the prefetch — the m97 stall).
__device__ __forceinline__ void bar_lds() {
    asm volatile("s_waitcnt lgkmcnt(0)" ::: "memory");
    __builtin_amdgcn_sched_barrier(0);
    __builtin_amdgcn_s_barrier();
    __builtin_amdgcn_sched_barrier(0);
}

// ---------------------------------------------------------------------------
// Kernel 0: vectorized f32 -> bf16 conversion of x, Wq, Wk, Wv, Er.
// ---------------------------------------------------------------------------
__global__ __launch_bounds__(256) void cvt_bf16(
    const float* __restrict__ x,  const float* __restrict__ wq,
    const float* __restrict__ wk, const float* __restrict__ wv,
    const float* __restrict__ er,
    unsigned short* __restrict__ xb, unsigned short* __restrict__ wb,
    unsigned short* __restrict__ erb)
{
    const int NX = 4194304 / 8, NW = 1048576 / 8, NE = 131072 / 8;
    const int total = NX + 3 * NW + NE;
    for (int i8 = blockIdx.x * 256 + threadIdx.x; i8 < total; i8 += gridDim.x * 256) {
        const float* src; unsigned short* dst; int off;
        if      (i8 < NX)          { src = x;  dst = xb;            off = i8; }
        else if (i8 < NX + NW)     { src = wq; dst = wb;            off = i8 - NX; }
        else if (i8 < NX + 2 * NW) { src = wk; dst = wb + 1048576;  off = i8 - NX - NW; }
        else if (i8 < NX + 3 * NW) { src = wv; dst = wb + 2097152;  off = i8 - NX - 2 * NW; }
        else                       { src = er; dst = erb;           off = i8 - NX - 3 * NW; }
        ((bf16x8*)dst)[off] = load8f_to_bf(src + (size_t)off * 8);
    }
}

// ---------------------------------------------------------------------------
// Kernel 1 (fast path): QKV projection from pre-converted bf16 inputs.
// ---------------------------------------------------------------------------
__global__ __launch_bounds__(256) void proj_kernel_bf(
    const unsigned short* __restrict__ xb, const unsigned short* __restrict__ wb,
    unsigned short* __restrict__ Qb, unsigned short* __restrict__ Kb,
    unsigned short* __restrict__ Vt)
{
    const int tid  = threadIdx.x;
    const int lane = tid & 63;
    const int w    = tid >> 6;
    const int wr   = w >> 1;
    const int wc   = w & 1;
    const int m0   = blockIdx.x * 128 + wr * 64;
    const int c0   = blockIdx.y * 128 + wc * 64;
    const int wsel = c0 >> 10;
    const int f0   = c0 & 1023;
    const unsigned short* __restrict__ W = wb + (size_t)wsel * 1048576;

    const int lr = lane & 15;
    const int lk = (lane >> 4) * 8;

    f32x4 acc[4][4];
#pragma unroll
    for (int i = 0; i < 4; i++)
#pragma unroll
        for (int n = 0; n < 4; n++) acc[i][n] = (f32x4){0.f, 0.f, 0.f, 0.f};

    for (int k0 = 0; k0 < 1024; k0 += 32) {
        bf16x8 a[4], b[4];
#pragma unroll
        for (int i = 0; i < 4; i++)
            a[i] = *(const bf16x8*)&xb[(size_t)(m0 + i * 16 + lr) * 1024 + k0 + lk];
#pragma unroll
        for (int n = 0; n < 4; n++)
            b[n] = *(const bf16x8*)&W[(size_t)(f0 + n * 16 + lr) * 1024 + k0 + lk];
#pragma unroll
        for (int i = 0; i < 4; i++)
#pragma unroll
            for (int n = 0; n < 4; n++)
                acc[i][n] = __builtin_amdgcn_mfma_f32_16x16x32_bf16(a[i], b[n], acc[i][n], 0, 0, 0);
    }

    const int g = lane >> 4;
#pragma unroll
    for (int i = 0; i < 4; i++) {
#pragma unroll
        for (int n = 0; n < 4; n++) {
#pragma unroll
            for (int j = 0; j < 4; j++) {
                int row_m = m0 + i * 16 + g * 4 + j;
                int c     = c0 + n * 16 + lr;
                int f     = c & 1023;
                int h     = f >> 6;
                int dd    = f & 63;
                int bb    = row_m >> 11;
                int s     = row_m & 2047;
                int bh    = bb * 16 + h;
                unsigned short bv = f2bf(acc[i][n][j]);
                if (wsel == 0)      Qb[((size_t)bh * 2048 + s) * 64 + dd] = bv;
                else if (wsel == 1) Kb[((size_t)bh * 2048 + s) * 64 + dd] = bv;
                else                Vt[((size_t)bh * 64 + dd) * 2048 + s] = bv;
            }
        }
    }
}

// ---------------------------------------------------------------------------
// Kernel 1 (fallback): f32 inputs with in-loop convert.
// ---------------------------------------------------------------------------
__global__ __launch_bounds__(256) void proj_kernel_f32(
    const float* __restrict__ x,
    const float* __restrict__ Wq, const float* __restrict__ Wk,
    const float* __restrict__ Wv,
    unsigned short* __restrict__ Qb, unsigned short* __restrict__ Kb,
    unsigned short* __restrict__ Vt)
{
    const int tid  = threadIdx.x;
    const int lane = tid & 63;
    const int w    = tid >> 6;
    const int wr   = w >> 1;
    const int wc   = w & 1;
    const int m0   = blockIdx.x * 128 + wr * 64;
    const int c0   = blockIdx.y * 128 + wc * 64;
    const int wsel = c0 >> 10;
    const int f0   = c0 & 1023;
    const float* __restrict__ W = (wsel == 0) ? Wq : (wsel == 1) ? Wk : Wv;

    const int lr = lane & 15;
    const int lk = (lane >> 4) * 8;

    f32x4 acc[4][4];
#pragma unroll
    for (int i = 0; i < 4; i++)
#pragma unroll
        for (int n = 0; n < 4; n++) acc[i][n] = (f32x4){0.f, 0.f, 0.f, 0.f};

    for (int k0 = 0; k0 < 1024; k0 += 32) {
        bf16x8 a[4], b[4];
#pragma unroll
        for (int i = 0; i < 4; i++)
            a[i] = load8f_to_bf(&x[(size_t)(m0 + i * 16 + lr) * 1024 + k0 + lk]);
#pragma unroll
        for (int n = 0; n < 4; n++)
            b[n] = load8f_to_bf(&W[(size_t)(f0 + n * 16 + lr) * 1024 + k0 + lk]);
#pragma unroll
        for (int i = 0; i < 4; i++)
#pragma unroll
            for (int n = 0; n < 4; n++)
                acc[i][n] = __builtin_amdgcn_mfma_f32_16x16x32_bf16(a[i], b[n], acc[i][n], 0, 0, 0);
    }

    const int g = lane >> 4;
#pragma unroll
    for (int i = 0; i < 4; i++) {
#pragma unroll
        for (int n = 0; n < 4; n++) {
#pragma unroll
            for (int j = 0; j < 4; j++) {
                int row_m = m0 + i * 16 + g * 4 + j;
                int c     = c0 + n * 16 + lr;
                int f     = c & 1023;
                int h     = f >> 6;
                int dd    = f & 63;
                int bb    = row_m >> 11;
                int s     = row_m & 2047;
                int bh    = bb * 16 + h;
                unsigned short bv = f2bf(acc[i][n][j]);
                if (wsel == 0)      Qb[((size_t)bh * 2048 + s) * 64 + dd] = bv;
                else if (wsel == 1) Kb[((size_t)bh * 2048 + s) * 64 + dd] = bv;
                else                Vt[((size_t)bh * 64 + dd) * 2048 + s] = bv;
            }
        }
    }
}

__global__ void cvt_er(const float* __restrict__ Er, unsigned short* __restrict__ Erb, int n)
{
    int i = blockIdx.x * 256 + threadIdx.x;
    if (i < n) Erb[i] = f2bf(Er[i]);
}

// ---------------------------------------------------------------------------
// Kernel 2: flash attention — 4-wave blocks, LDS-staged K/V/Er (shared by all
// waves), swapped-operand strip math identical to r11, reg-resident P.
// Block = 256 thr = 4 waves; wave w owns strip rows [q0+16w, q0+16w+16).
// Per 64-key tile: stage K 8KB + V 8KB + Er-window 16KB (128 rows) into LDS,
// XOR-swizzled (idx ^= (row&7)<<3 in ushorts) to break the 128B-row 16-way
// bank conflict (G4). T14: next tile's stage loads issued right after this
// tile's ds_writes; bar_lds() does not drain vmcnt, so they fly across
// barriers. Strip-w Er window = staged rows [48-16w, 48-16w+79].
// Grid 1024 = (xcd:3 | b2:2 | qt:5), heavy-first, XCD-pinned K/V (2MB/XCD).
// LDS: 32KB stage + 23KB Rt = 55.8KB -> 2 blocks/CU (8 waves/CU).
// ---------------------------------------------------------------------------
__global__ __launch_bounds__(256) void attn_kernel(
    const unsigned short* __restrict__ Qb, const unsigned short* __restrict__ Kb,
    const unsigned short* __restrict__ Vt, const unsigned short* __restrict__ Erb,
    float* __restrict__ out)
{
    __shared__ __align__(16) unsigned short Kl[64 * 64];
    __shared__ __align__(16) unsigned short Vl[64 * 64];
    __shared__ __align__(16) unsigned short El[128 * 64];
    __shared__ __align__(16) float          Rt[4][80][18];

    const int tid  = threadIdx.x;
    const int lane = tid & 63;
    const int w    = tid >> 6;

    const int i0  = blockIdx.x;
    const int xcd = i0 & 7;              // XCD pin: bh in {4*xcd..4*xcd+3}
    const int b2  = (i0 >> 3) & 3;
    const int qt  = 31 - (i0 >> 5);      // heavy first
    const int bh  = (xcd << 2) | b2;

    const int lr = lane & 15;
    const int g  = lane >> 4;
    const int lk = g * 8;

    const unsigned short* __restrict__ Qrow = Qb + (size_t)bh * 2048 * 64;
    const unsigned short* __restrict__ Krow = Kb + (size_t)bh * 2048 * 64;
    const unsigned short* __restrict__ Vrow = Vt + (size_t)bh * 64 * 2048;

    const float SCL = 0.125f * 1.44269504089f;  // (1/sqrt(64)) * log2(e)
    const int bb  = bh >> 4;
    const int h   = bh & 15;
    const int q0  = qt * 64;
    const int q0w = q0 + w * 16;
    const int eoff = 48 - 16 * w;               // strip-w window base in El

    bf16x8 aq[2];
#pragma unroll
    for (int kk = 0; kk < 2; kk++)
        aq[kk] = *(const bf16x8*)&Qrow[(size_t)(q0w + lr) * 64 + kk * 32 + lk];

    f32x4 o[4];
#pragma unroll
    for (int m = 0; m < 4; m++) o[m] = (f32x4){0.f, 0.f, 0.f, 0.f};
    float mrow = -1e30f, lsum = 0.f;

    // ---- T14 stage registers (global -> reg, written to LDS next phase) ----
    bf16x8 sk[2], sv[2], se[4];
    auto stage_load = [&](int kt) {
        const int k0  = kt * 64;
        const int rbT = 2047 + k0 - q0 - 63;     // >= 0 (q0 <= 1984)
#pragma unroll
        for (int i = 0; i < 2; i++) {
            int c = i * 256 + tid, kr = c >> 3, o8 = (c & 7) * 8;
            sk[i] = *(const bf16x8*)&Krow[(size_t)(k0 + kr) * 64 + o8];
        }
#pragma unroll
        for (int i = 0; i < 2; i++) {
            int c = i * 256 + tid, d = c >> 3, o8 = (c & 7) * 8;
            sv[i] = *(const bf16x8*)&Vrow[(size_t)d * 2048 + k0 + o8];
        }
#pragma unroll
        for (int i = 0; i < 4; i++) {
            int c = i * 256 + tid, wr_ = c >> 3, o8 = (c & 7) * 8;
            int rr = rbT + wr_; rr = rr > 2047 ? 2047 : rr;
            se[i] = *(const bf16x8*)&Erb[(size_t)rr * 64 + o8];
        }
    };
    auto stage_write = [&]() {
#pragma unroll
        for (int i = 0; i < 2; i++) {
            int c = i * 256 + tid, kr = c >> 3, o8 = (c & 7) * 8;
            *(bf16x8*)&Kl[(kr * 64 + o8) ^ ((kr & 7) << 3)] = sk[i];
        }
#pragma unroll
        for (int i = 0; i < 2; i++) {
            int c = i * 256 + tid, d = c >> 3, o8 = (c & 7) * 8;
            *(bf16x8*)&Vl[(d * 64 + o8) ^ ((d & 7) << 3)] = sv[i];
        }
#pragma unroll
        for (int i = 0; i < 4; i++) {
            int c = i * 256 + tid, wr_ = c >> 3, o8 = (c & 7) * 8;
            *(bf16x8*)&El[(wr_ * 64 + o8) ^ ((wr_ & 7) << 3)] = se[i];
        }
    };

    stage_load(0);

#pragma unroll 1
    for (int kt = 0; kt <= qt; ++kt) {
        const int k0 = kt * 64;

        bar_lds();                 // A: prior tile's LDS reads done (WAR)
        stage_write();
        if (kt < qt) stage_load(kt + 1);   // T14: in flight across barriers
        bar_lds();                 // B: stage visible to all waves

        // ---- S^T = K·Q^T and R^T = Er·Q^T (frags from LDS) ----
        f32x4 s[4], r[5];
#pragma unroll
        for (int n = 0; n < 4; n++) s[n] = (f32x4){0.f, 0.f, 0.f, 0.f};
#pragma unroll
        for (int n = 0; n < 5; n++) r[n] = (f32x4){0.f, 0.f, 0.f, 0.f};
#pragma unroll
        for (int kk = 0; kk < 2; kk++) {
            bf16x8 kb[4], be[5];
#pragma unroll
            for (int n = 0; n < 4; n++) {
                int kr = n * 16 + lr;
                kb[n] = *(const bf16x8*)&Kl[(kr * 64 + kk * 32 + lk) ^ ((kr & 7) << 3)];
            }
#pragma unroll
            for (int n = 0; n < 5; n++) {
                int er = eoff + n * 16 + lr;
                be[n] = *(const bf16x8*)&El[(er * 64 + kk * 32 + lk) ^ ((er & 7) << 3)];
            }
#pragma unroll
            for (int n = 0; n < 4; n++)
                s[n] = __builtin_amdgcn_mfma_f32_16x16x32_bf16(kb[n], aq[kk], s[n], 0, 0, 0);
#pragma unroll
            for (int n = 0; n < 5; n++)
                r[n] = __builtin_amdgcn_mfma_f32_16x16x32_bf16(be[n], aq[kk], r[n], 0, 0, 0);
        }

        // ---- Rt skew exchange (per-wave region) ----
#pragma unroll
        for (int n = 0; n < 5; n++)
#pragma unroll
            for (int j = 0; j < 4; j++)
                Rt[w][n * 16 + g * 4 + j][lr] = r[n][j];

        bar_lds();                 // C: Rt RAW (also compiler fence, rule 18)

        // ---- combine + causal mask (in-lane) ----
        float pmax = -1e30f;
#pragma unroll
        for (int n = 0; n < 4; n++) {
#pragma unroll
            for (int j = 0; j < 4; j++) {
                int wd = n * 16 + g * 4 + j + 15 - lr;
                float sc = (s[n][j] + Rt[w][wd][lr]) * SCL;
                if (k0 + n * 16 + g * 4 + j > q0w + lr) sc = -1e30f;
                s[n][j] = sc;
                pmax = fmaxf(pmax, sc);
            }
        }

        // ---- T13: reduce + rescale only when the row max grows ----
        if (__any(pmax > mrow + 4.0f)) {
            pmax = fmaxf(pmax, __shfl_xor(pmax, 16));
            pmax = fmaxf(pmax, __shfl_xor(pmax, 32));
            float mn   = fmaxf(mrow, pmax);
            float corr = exp2f(mrow - mn);
            mrow = mn;
            lsum *= corr;
#pragma unroll
            for (int j = 0; j < 4; j++) {
                float cj = __shfl(corr, g * 4 + j);
#pragma unroll
                for (int m = 0; m < 4; m++) o[m][j] *= cj;
            }
        }

        // ---- exp + pack P into A-fragments (registers) ----
        float rs = 0.f;
        bf16x4 pa[4];
#pragma unroll
        for (int n = 0; n < 4; n++)
#pragma unroll
            for (int j = 0; j < 4; j++) {
                float pv = exp2f(s[n][j] - mrow);
                rs += pv;
                pa[n][j] = (short)f2bf(pv);
            }
        lsum += rs;

        // ---- P @ V : V B-fragments from LDS ----
#pragma unroll
        for (int m = 0; m < 4; m++) {
#pragma unroll
            for (int n = 0; n < 4; n++) {
                int d = 16 * m + lr;
                bf16x4 vb = *(const bf16x4*)&Vl[(d * 64 + 16 * n + 4 * g) ^ ((d & 7) << 3)];
                o[m] = __builtin_amdgcn_mfma_f32_16x16x16bf16_1k(pa[n], vb, o[m], 0, 0, 0);
            }
        }
    }

    // ---- epilogue: reduce partial lsum over g-lanes, store f32 ----
    float ls = lsum;
    ls += __shfl_xor(ls, 16);
    ls += __shfl_xor(ls, 32);
    float linv = 1.0f / ls;
#pragma unroll
    for (int j = 0; j < 4; j++) {
        float lj = __shfl(linv, g * 4 + j);
#pragma unroll
        for (int m = 0; m < 4; m++) {
            int row = q0w + g * 4 + j;
            int col = h * 64 + 16 * m + lr;
            out[((size_t)bb * 2048 + row) * 1024 + col] = o[m][j] * lj;
        }
    }
}

// ---------------------------------------------------------------------------
extern "C" void kernel_launch(void* const* d_in, const int* in_sizes, int n_in,
                              void* d_out, int out_size, void* d_ws, size_t ws_size,
                              hipStream_t stream)
{
    const float* x  = (const float*)d_in[0];
    const float* Wq = (const float*)d_in[1];
    const float* Wk = (const float*)d_in[2];
    const float* Wv = (const float*)d_in[3];
    const float* Er = (const float*)d_in[4];
    float* out = (float*)d_out;   // f32 output (reference returns jnp.float32)

    char* ws = (char*)d_ws;
    const size_t MB = 1024 * 1024;
    unsigned short* Qb  = (unsigned short*)(ws);            // 8 MB
    unsigned short* Kb  = (unsigned short*)(ws + 8  * MB);  // 8 MB
    unsigned short* Vt  = (unsigned short*)(ws + 16 * MB);  // 8 MB
    unsigned short* Erb = (unsigned short*)(ws + 24 * MB);  // 256 KB
    unsigned short* xb  = (unsigned short*)(ws + 25 * MB);  // 8 MB
    unsigned short* wb  = (unsigned short*)(ws + 33 * MB);  // 6 MB  (total 39 MB)

    if (ws_size >= (size_t)39 * MB) {
        cvt_bf16<<<dim3(1024), dim3(256), 0, stream>>>(x, Wq, Wk, Wv, Er, xb, wb, Erb);
        proj_kernel_bf<<<dim3(32, 24), dim3(256), 0, stream>>>(xb, wb, Qb, Kb, Vt);
    } else {
        cvt_er<<<dim3(512), dim3(256), 0, stream>>>(Er, Erb, 2048 * 64);
        proj_kernel_f32<<<dim3(32, 24), dim3(256), 0, stream>>>(x, Wq, Wk, Wv, Qb, Kb, Vt);
    }
    attn_kernel<<<dim3(1024), dim3(256), 0, stream>>>(Qb, Kb, Vt, Erb, out);
}

// Round 13
// 140.416 us; speedup vs baseline: 2.8720x; 1.4268x over previous
//
#include <hip/hip_runtime.h>
#include <hip/hip_bf16.h>
#include <stdint.h>

// Problem constants
#define S_LEN 2048
#define EMB   1024
#define NH    16
#define DH    64
#define BATCH 2

typedef short bf16x8 __attribute__((ext_vector_type(8)));
typedef short bf16x4 __attribute__((ext_vector_type(4)));
typedef float f32x4  __attribute__((ext_vector_type(4)));

__device__ __forceinline__ unsigned short f2bf(float f) {
    union { float f; unsigned int u; } v; v.f = f;
    unsigned int r = v.u + 0x7FFFu + ((v.u >> 16) & 1u);
    return (unsigned short)(r >> 16);
}

__device__ __forceinline__ bf16x8 load8f_to_bf(const float* __restrict__ p) {
    const float4* p4 = (const float4*)p;
    float4 x0 = p4[0];
    float4 x1 = p4[1];
    bf16x8 r;
    r[0] = (short)f2bf(x0.x); r[1] = (short)f2bf(x0.y);
    r[2] = (short)f2bf(x0.z); r[3] = (short)f2bf(x0.w);
    r[4] = (short)f2bf(x1.x); r[5] = (short)f2bf(x1.y);
    r[6] = (short)f2bf(x1.z); r[7] = (short)f2bf(x1.w);
    return r;
}

// LDS barrier that does NOT drain vmcnt (attn T14 stage-prefetch).
__device__ __forceinline__ void bar_lds() {
    asm volatile("s_waitcnt lgkmcnt(0)" ::: "memory");
    __builtin_amdgcn_sched_barrier(0);
    __builtin_amdgcn_s_barrier();
    __builtin_amdgcn_sched_barrier(0);
}

// async global->LDS, 16B per lane; dest = wave-uniform base + lane*16.
__device__ __forceinline__ void gload_lds16(const unsigned short* g, unsigned short* l) {
    __builtin_amdgcn_global_load_lds(
        (const __attribute__((address_space(1))) unsigned int*)g,
        (__attribute__((address_space(3))) unsigned int*)l, 16, 0, 0);
}

// ---------------------------------------------------------------------------
// Kernel 0: vectorized f32 -> bf16 conversion of x, Wq, Wk, Wv, Er.
// ---------------------------------------------------------------------------
__global__ __launch_bounds__(256) void cvt_bf16(
    const float* __restrict__ x,  const float* __restrict__ wq,
    const float* __restrict__ wk, const float* __restrict__ wv,
    const float* __restrict__ er,
    unsigned short* __restrict__ xb, unsigned short* __restrict__ wb,
    unsigned short* __restrict__ erb)
{
    const int NX = 4194304 / 8, NW = 1048576 / 8, NE = 131072 / 8;
    const int total = NX + 3 * NW + NE;
    for (int i8 = blockIdx.x * 256 + threadIdx.x; i8 < total; i8 += gridDim.x * 256) {
        const float* src; unsigned short* dst; int off;
        if      (i8 < NX)          { src = x;  dst = xb;            off = i8; }
        else if (i8 < NX + NW)     { src = wq; dst = wb;            off = i8 - NX; }
        else if (i8 < NX + 2 * NW) { src = wk; dst = wb + 1048576;  off = i8 - NX - NW; }
        else if (i8 < NX + 3 * NW) { src = wv; dst = wb + 2097152;  off = i8 - NX - 2 * NW; }
        else                       { src = er; dst = erb;           off = i8 - NX - 3 * NW; }
        ((bf16x8*)dst)[off] = load8f_to_bf(src + (size_t)off * 8);
    }
}

// ---------------------------------------------------------------------------
// Kernel 1 (fast path): QKV projection, m97-structure LDS-staged GEMM.
// Tile 128x128, BK=64, 16 K-steps, 2 barriers/step. Staging via
// global_load_lds (linear dest); BK=64 rows are 128B -> G4 16-way conflict,
// fixed per rule 21: inverse-swizzled SOURCE (colchunk ^= row&7) + same XOR
// on ds_read. Each wave computes a 64x64 quadrant (wr,wc).
// ---------------------------------------------------------------------------
__global__ __launch_bounds__(256) void proj_kernel_bf(
    const unsigned short* __restrict__ xb, const unsigned short* __restrict__ wb,
    unsigned short* __restrict__ Qb, unsigned short* __restrict__ Kb,
    unsigned short* __restrict__ Vt)
{
    __shared__ __align__(16) unsigned short Al[128 * 64];   // 16 KB
    __shared__ __align__(16) unsigned short Bl[128 * 64];   // 16 KB

    const int tid  = threadIdx.x;
    const int lane = tid & 63;
    const int w    = tid >> 6;
    const int wr   = w >> 1;
    const int wc   = w & 1;
    const int m0   = blockIdx.x * 128;
    const int c0   = blockIdx.y * 128;
    const int wsel = c0 >> 10;
    const int f0   = c0 & 1023;
    const unsigned short* __restrict__ W = wb + (size_t)wsel * 1048576;

    const int lr = lane & 15;
    const int g  = lane >> 4;

    // staging geometry: issue i, chunk c = i*256+tid; row = i*32 + (tid>>3),
    // dest slot = tid&7; source col-chunk = (tid&7) ^ (row&7)  [involution]
    const int srow8 = tid >> 3;                           // 0..31
    const int scol  = (((tid & 7) ^ (srow8 & 7))) * 8;    // pre-swizzled, elems

    f32x4 acc[4][4];
#pragma unroll
    for (int i = 0; i < 4; i++)
#pragma unroll
        for (int n = 0; n < 4; n++) acc[i][n] = (f32x4){0.f, 0.f, 0.f, 0.f};

    for (int k0 = 0; k0 < 1024; k0 += 64) {
        __syncthreads();   // WAR: previous step's LDS reads complete
#pragma unroll
        for (int i = 0; i < 4; i++) {
            gload_lds16(&xb[(size_t)(m0 + i * 32 + srow8) * 1024 + k0 + scol],
                        &Al[(i * 4 + w) * 512]);
            gload_lds16(&W [(size_t)(f0 + i * 32 + srow8) * 1024 + k0 + scol],
                        &Bl[(i * 4 + w) * 512]);
        }
        __syncthreads();   // RAW: barrier drains vmcnt -> stage visible

#pragma unroll
        for (int kk = 0; kk < 2; kk++) {
            bf16x8 a[4], b[4];
#pragma unroll
            for (int i = 0; i < 4; i++) {
                int ar = wr * 64 + i * 16 + lr;
                a[i] = *(const bf16x8*)&Al[ar * 64 + (((kk * 4 + g) ^ (ar & 7)) * 8)];
            }
#pragma unroll
            for (int n = 0; n < 4; n++) {
                int br = wc * 64 + n * 16 + lr;
                b[n] = *(const bf16x8*)&Bl[br * 64 + (((kk * 4 + g) ^ (br & 7)) * 8)];
            }
#pragma unroll
            for (int i = 0; i < 4; i++)
#pragma unroll
                for (int n = 0; n < 4; n++)
                    acc[i][n] = __builtin_amdgcn_mfma_f32_16x16x32_bf16(a[i], b[n], acc[i][n], 0, 0, 0);
        }
    }

    // Epilogue: C layout col=lane&15, row=(lane>>4)*4+reg; scatter to Q/K/Vt.
#pragma unroll
    for (int i = 0; i < 4; i++) {
#pragma unroll
        for (int n = 0; n < 4; n++) {
#pragma unroll
            for (int j = 0; j < 4; j++) {
                int row_m = m0 + wr * 64 + i * 16 + g * 4 + j;
                int c     = c0 + wc * 64 + n * 16 + lr;
                int f     = c & 1023;
                int h     = f >> 6;
                int dd    = f & 63;
                int bb    = row_m >> 11;
                int s     = row_m & 2047;
                int bh    = bb * 16 + h;
                unsigned short bv = f2bf(acc[i][n][j]);
                if (wsel == 0)      Qb[((size_t)bh * 2048 + s) * 64 + dd] = bv;
                else if (wsel == 1) Kb[((size_t)bh * 2048 + s) * 64 + dd] = bv;
                else                Vt[((size_t)bh * 64 + dd) * 2048 + s] = bv;
            }
        }
    }
}

// ---------------------------------------------------------------------------
// Kernel 1 (fallback): f32 inputs with in-loop convert (direct loads).
// ---------------------------------------------------------------------------
__global__ __launch_bounds__(256) void proj_kernel_f32(
    const float* __restrict__ x,
    const float* __restrict__ Wq, const float* __restrict__ Wk,
    const float* __restrict__ Wv,
    unsigned short* __restrict__ Qb, unsigned short* __restrict__ Kb,
    unsigned short* __restrict__ Vt)
{
    const int tid  = threadIdx.x;
    const int lane = tid & 63;
    const int w    = tid >> 6;
    const int wr   = w >> 1;
    const int wc   = w & 1;
    const int m0   = blockIdx.x * 128 + wr * 64;
    const int c0   = blockIdx.y * 128 + wc * 64;
    const int wsel = c0 >> 10;
    const int f0   = c0 & 1023;
    const float* __restrict__ W = (wsel == 0) ? Wq : (wsel == 1) ? Wk : Wv;

    const int lr = lane & 15;
    const int lk = (lane >> 4) * 8;

    f32x4 acc[4][4];
#pragma unroll
    for (int i = 0; i < 4; i++)
#pragma unroll
        for (int n = 0; n < 4; n++) acc[i][n] = (f32x4){0.f, 0.f, 0.f, 0.f};

    for (int k0 = 0; k0 < 1024; k0 += 32) {
        bf16x8 a[4], b[4];
#pragma unroll
        for (int i = 0; i < 4; i++)
            a[i] = load8f_to_bf(&x[(size_t)(m0 + i * 16 + lr) * 1024 + k0 + lk]);
#pragma unroll
        for (int n = 0; n < 4; n++)
            b[n] = load8f_to_bf(&W[(size_t)(f0 + n * 16 + lr) * 1024 + k0 + lk]);
#pragma unroll
        for (int i = 0; i < 4; i++)
#pragma unroll
            for (int n = 0; n < 4; n++)
                acc[i][n] = __builtin_amdgcn_mfma_f32_16x16x32_bf16(a[i], b[n], acc[i][n], 0, 0, 0);
    }

    const int g = lane >> 4;
#pragma unroll
    for (int i = 0; i < 4; i++) {
#pragma unroll
        for (int n = 0; n < 4; n++) {
#pragma unroll
            for (int j = 0; j < 4; j++) {
                int row_m = m0 + i * 16 + g * 4 + j;
                int c     = c0 + n * 16 + lr;
                int f     = c & 1023;
                int h     = f >> 6;
                int dd    = f & 63;
                int bb    = row_m >> 11;
                int s     = row_m & 2047;
                int bh    = bb * 16 + h;
                unsigned short bv = f2bf(acc[i][n][j]);
                if (wsel == 0)      Qb[((size_t)bh * 2048 + s) * 64 + dd] = bv;
                else if (wsel == 1) Kb[((size_t)bh * 2048 + s) * 64 + dd] = bv;
                else                Vt[((size_t)bh * 64 + dd) * 2048 + s] = bv;
            }
        }
    }
}

__global__ void cvt_er(const float* __restrict__ Er, unsigned short* __restrict__ Erb, int n)
{
    int i = blockIdx.x * 256 + threadIdx.x;
    if (i < n) Erb[i] = f2bf(Er[i]);
}

// ---------------------------------------------------------------------------
// Kernel 2: flash attention — 4-wave blocks, LDS-staged K/V/Er (unchanged
// from r12, which cut attn 193 -> ~80 us).
// ---------------------------------------------------------------------------
__global__ __launch_bounds__(256) void attn_kernel(
    const unsigned short* __restrict__ Qb, const unsigned short* __restrict__ Kb,
    const unsigned short* __restrict__ Vt, const unsigned short* __restrict__ Erb,
    float* __restrict__ out)
{
    __shared__ __align__(16) unsigned short Kl[64 * 64];
    __shared__ __align__(16) unsigned short Vl[64 * 64];
    __shared__ __align__(16) unsigned short El[128 * 64];
    __shared__ __align__(16) float          Rt[4][80][18];

    const int tid  = threadIdx.x;
    const int lane = tid & 63;
    const int w    = tid >> 6;

    const int i0  = blockIdx.x;
    const int xcd = i0 & 7;              // XCD pin: bh in {4*xcd..4*xcd+3}
    const int b2  = (i0 >> 3) & 3;
    const int qt  = 31 - (i0 >> 5);      // heavy first
    const int bh  = (xcd << 2) | b2;

    const int lr = lane & 15;
    const int g  = lane >> 4;
    const int lk = g * 8;

    const unsigned short* __restrict__ Qrow = Qb + (size_t)bh * 2048 * 64;
    const unsigned short* __restrict__ Krow = Kb + (size_t)bh * 2048 * 64;
    const unsigned short* __restrict__ Vrow = Vt + (size_t)bh * 64 * 2048;

    const float SCL = 0.125f * 1.44269504089f;  // (1/sqrt(64)) * log2(e)
    const int bb  = bh >> 4;
    const int h   = bh & 15;
    const int q0  = qt * 64;
    const int q0w = q0 + w * 16;
    const int eoff = 48 - 16 * w;               // strip-w window base in El

    bf16x8 aq[2];
#pragma unroll
    for (int kk = 0; kk < 2; kk++)
        aq[kk] = *(const bf16x8*)&Qrow[(size_t)(q0w + lr) * 64 + kk * 32 + lk];

    f32x4 o[4];
#pragma unroll
    for (int m = 0; m < 4; m++) o[m] = (f32x4){0.f, 0.f, 0.f, 0.f};
    float mrow = -1e30f, lsum = 0.f;

    // ---- T14 stage registers (global -> reg, written to LDS next phase) ----
    bf16x8 sk[2], sv[2], se[4];
    auto stage_load = [&](int kt) {
        const int k0  = kt * 64;
        const int rbT = 2047 + k0 - q0 - 63;     // >= 0 (q0 <= 1984)
#pragma unroll
        for (int i = 0; i < 2; i++) {
            int c = i * 256 + tid, kr = c >> 3, o8 = (c & 7) * 8;
            sk[i] = *(const bf16x8*)&Krow[(size_t)(k0 + kr) * 64 + o8];
        }
#pragma unroll
        for (int i = 0; i < 2; i++) {
            int c = i * 256 + tid, d = c >> 3, o8 = (c & 7) * 8;
            sv[i] = *(const bf16x8*)&Vrow[(size_t)d * 2048 + k0 + o8];
        }
#pragma unroll
        for (int i = 0; i < 4; i++) {
            int c = i * 256 + tid, wr_ = c >> 3, o8 = (c & 7) * 8;
            int rr = rbT + wr_; rr = rr > 2047 ? 2047 : rr;
            se[i] = *(const bf16x8*)&Erb[(size_t)rr * 64 + o8];
        }
    };
    auto stage_write = [&]() {
#pragma unroll
        for (int i = 0; i < 2; i++) {
            int c = i * 256 + tid, kr = c >> 3, o8 = (c & 7) * 8;
            *(bf16x8*)&Kl[(kr * 64 + o8) ^ ((kr & 7) << 3)] = sk[i];
        }
#pragma unroll
        for (int i = 0; i < 2; i++) {
            int c = i * 256 + tid, d = c >> 3, o8 = (c & 7) * 8;
            *(bf16x8*)&Vl[(d * 64 + o8) ^ ((d & 7) << 3)] = sv[i];
        }
#pragma unroll
        for (int i = 0; i < 4; i++) {
            int c = i * 256 + tid, wr_ = c >> 3, o8 = (c & 7) * 8;
            *(bf16x8*)&El[(wr_ * 64 + o8) ^ ((wr_ & 7) << 3)] = se[i];
        }
    };

    stage_load(0);

#pragma unroll 1
    for (int kt = 0; kt <= qt; ++kt) {
        const int k0 = kt * 64;

        bar_lds();                 // A: prior tile's LDS reads done (WAR)
        stage_write();
        if (kt < qt) stage_load(kt + 1);   // T14: in flight across barriers
        bar_lds();                 // B: stage visible to all waves

        // ---- S^T = K·Q^T and R^T = Er·Q^T (frags from LDS) ----
        f32x4 s[4], r[5];
#pragma unroll
        for (int n = 0; n < 4; n++) s[n] = (f32x4){0.f, 0.f, 0.f, 0.f};
#pragma unroll
        for (int n = 0; n < 5; n++) r[n] = (f32x4){0.f, 0.f, 0.f, 0.f};
#pragma unroll
        for (int kk = 0; kk < 2; kk++) {
            bf16x8 kb[4], be[5];
#pragma unroll
            for (int n = 0; n < 4; n++) {
                int kr = n * 16 + lr;
                kb[n] = *(const bf16x8*)&Kl[(kr * 64 + kk * 32 + lk) ^ ((kr & 7) << 3)];
            }
#pragma unroll
            for (int n = 0; n < 5; n++) {
                int er = eoff + n * 16 + lr;
                be[n] = *(const bf16x8*)&El[(er * 64 + kk * 32 + lk) ^ ((er & 7) << 3)];
            }
#pragma unroll
            for (int n = 0; n < 4; n++)
                s[n] = __builtin_amdgcn_mfma_f32_16x16x32_bf16(kb[n], aq[kk], s[n], 0, 0, 0);
#pragma unroll
            for (int n = 0; n < 5; n++)
                r[n] = __builtin_amdgcn_mfma_f32_16x16x32_bf16(be[n], aq[kk], r[n], 0, 0, 0);
        }

        // ---- Rt skew exchange (per-wave region) ----
#pragma unroll
        for (int n = 0; n < 5; n++)
#pragma unroll
            for (int j = 0; j < 4; j++)
                Rt[w][n * 16 + g * 4 + j][lr] = r[n][j];

        bar_lds();                 // C: Rt RAW (also compiler fence, rule 18)

        // ---- combine + causal mask (in-lane) ----
        float pmax = -1e30f;
#pragma unroll
        for (int n = 0; n < 4; n++) {
#pragma unroll
            for (int j = 0; j < 4; j++) {
                int wd = n * 16 + g * 4 + j + 15 - lr;
                float sc = (s[n][j] + Rt[w][wd][lr]) * SCL;
                if (k0 + n * 16 + g * 4 + j > q0w + lr) sc = -1e30f;
                s[n][j] = sc;
                pmax = fmaxf(pmax, sc);
            }
        }

        // ---- T13: reduce + rescale only when the row max grows ----
        if (__any(pmax > mrow + 4.0f)) {
            pmax = fmaxf(pmax, __shfl_xor(pmax, 16));
            pmax = fmaxf(pmax, __shfl_xor(pmax, 32));
            float mn   = fmaxf(mrow, pmax);
            float corr = exp2f(mrow - mn);
            mrow = mn;
            lsum *= corr;
#pragma unroll
            for (int j = 0; j < 4; j++) {
                float cj = __shfl(corr, g * 4 + j);
#pragma unroll
                for (int m = 0; m < 4; m++) o[m][j] *= cj;
            }
        }

        // ---- exp + pack P into A-fragments (registers) ----
        float rs = 0.f;
        bf16x4 pa[4];
#pragma unroll
        for (int n = 0; n < 4; n++)
#pragma unroll
            for (int j = 0; j < 4; j++) {
                float pv = exp2f(s[n][j] - mrow);
                rs += pv;
                pa[n][j] = (short)f2bf(pv);
            }
        lsum += rs;

        // ---- P @ V : V B-fragments from LDS ----
#pragma unroll
        for (int m = 0; m < 4; m++) {
#pragma unroll
            for (int n = 0; n < 4; n++) {
                int d = 16 * m + lr;
                bf16x4 vb = *(const bf16x4*)&Vl[(d * 64 + 16 * n + 4 * g) ^ ((d & 7) << 3)];
                o[m] = __builtin_amdgcn_mfma_f32_16x16x16bf16_1k(pa[n], vb, o[m], 0, 0, 0);
            }
        }
    }

    // ---- epilogue: reduce partial lsum over g-lanes, store f32 ----
    float ls = lsum;
    ls += __shfl_xor(ls, 16);
    ls += __shfl_xor(ls, 32);
    float linv = 1.0f / ls;
#pragma unroll
    for (int j = 0; j < 4; j++) {
        float lj = __shfl(linv, g * 4 + j);
#pragma unroll
        for (int m = 0; m < 4; m++) {
            int row = q0w + g * 4 + j;
            int col = h * 64 + 16 * m + lr;
            out[((size_t)bb * 2048 + row) * 1024 + col] = o[m][j] * lj;
        }
    }
}

// ---------------------------------------------------------------------------
extern "C" void kernel_launch(void* const* d_in, const int* in_sizes, int n_in,
                              void* d_out, int out_size, void* d_ws, size_t ws_size,
                              hipStream_t stream)
{
    const float* x  = (const float*)d_in[0];
    const float* Wq = (const float*)d_in[1];
    const float* Wk = (const float*)d_in[2];
    const float* Wv = (const float*)d_in[3];
    const float* Er = (const float*)d_in[4];
    float* out = (float*)d_out;   // f32 output (reference returns jnp.float32)

    char* ws = (char*)d_ws;
    const size_t MB = 1024 * 1024;
    unsigned short* Qb  = (unsigned short*)(ws);            // 8 MB
    unsigned short* Kb  = (unsigned short*)(ws + 8  * MB);  // 8 MB
    unsigned short* Vt  = (unsigned short*)(ws + 16 * MB);  // 8 MB
    unsigned short* Erb = (unsigned short*)(ws + 24 * MB);  // 256 KB
    unsigned short* xb  = (unsigned short*)(ws + 25 * MB);  // 8 MB
    unsigned short* wb  = (unsigned short*)(ws + 33 * MB);  // 6 MB  (total 39 MB)

    if (ws_size >= (size_t)39 * MB) {
        cvt_bf16<<<dim3(1024), dim3(256), 0, stream>>>(x, Wq, Wk, Wv, Er, xb, wb, Erb);
        proj_kernel_bf<<<dim3(32, 24), dim3(256), 0, stream>>>(xb, wb, Qb, Kb, Vt);
    } else {
        cvt_er<<<dim3(512), dim3(256), 0, stream>>>(Er, Erb, 2048 * 64);
        proj_kernel_f32<<<dim3(32, 24), dim3(256), 0, stream>>>(x, Wq, Wk, Wv, Qb, Kb, Vt);
    }
    attn_kernel<<<dim3(1024), dim3(256), 0, stream>>>(Qb, Kb, Vt, Erb, out);
}

// Round 14
// 130.321 us; speedup vs baseline: 3.0945x; 1.0775x over previous
//
#include <hip/hip_runtime.h>
#include <hip/hip_bf16.h>
#include <stdint.h>

// Problem constants
#define S_LEN 2048
#define EMB   1024
#define NH    16
#define DH    64
#define BATCH 2

typedef short bf16x8 __attribute__((ext_vector_type(8)));
typedef short bf16x4 __attribute__((ext_vector_type(4)));
typedef float f32x4  __attribute__((ext_vector_type(4)));

__device__ __forceinline__ unsigned short f2bf(float f) {
    union { float f; unsigned int u; } v; v.f = f;
    unsigned int r = v.u + 0x7FFFu + ((v.u >> 16) & 1u);
    return (unsigned short)(r >> 16);
}

// Compiler-native f32->bf16 (emits v_cvt; m240: scalar-cast path is fastest)
__device__ __forceinline__ short f2bf_fast(float f) {
    __hip_bfloat16 h = __float2bfloat16(f);
    return *reinterpret_cast<short*>(&h);
}

__device__ __forceinline__ bf16x8 load8f_to_bf(const float* __restrict__ p) {
    const float4* p4 = (const float4*)p;
    float4 x0 = p4[0];
    float4 x1 = p4[1];
    bf16x8 r;
    r[0] = (short)f2bf(x0.x); r[1] = (short)f2bf(x0.y);
    r[2] = (short)f2bf(x0.z); r[3] = (short)f2bf(x0.w);
    r[4] = (short)f2bf(x1.x); r[5] = (short)f2bf(x1.y);
    r[6] = (short)f2bf(x1.z); r[7] = (short)f2bf(x1.w);
    return r;
}

// LDS barrier that does NOT drain vmcnt (T14 stage-prefetch stays in flight).
__device__ __forceinline__ void bar_lds() {
    asm volatile("s_waitcnt lgkmcnt(0)" ::: "memory");
    __builtin_amdgcn_sched_barrier(0);
    __builtin_amdgcn_s_barrier();
    __builtin_amdgcn_sched_barrier(0);
}

// async global->LDS, 16B per lane; dest = wave-uniform base + lane*16.
__device__ __forceinline__ void gload_lds16(const unsigned short* g, unsigned short* l) {
    __builtin_amdgcn_global_load_lds(
        (const __attribute__((address_space(1))) unsigned int*)g,
        (__attribute__((address_space(3))) unsigned int*)l, 16, 0, 0);
}

// ---------------------------------------------------------------------------
// Kernel 0: vectorized f32 -> bf16 conversion of x, Wq, Wk, Wv, Er.
// ---------------------------------------------------------------------------
__global__ __launch_bounds__(256) void cvt_bf16(
    const float* __restrict__ x,  const float* __restrict__ wq,
    const float* __restrict__ wk, const float* __restrict__ wv,
    const float* __restrict__ er,
    unsigned short* __restrict__ xb, unsigned short* __restrict__ wb,
    unsigned short* __restrict__ erb)
{
    const int NX = 4194304 / 8, NW = 1048576 / 8, NE = 131072 / 8;
    const int total = NX + 3 * NW + NE;
    for (int i8 = blockIdx.x * 256 + threadIdx.x; i8 < total; i8 += gridDim.x * 256) {
        const float* src; unsigned short* dst; int off;
        if      (i8 < NX)          { src = x;  dst = xb;            off = i8; }
        else if (i8 < NX + NW)     { src = wq; dst = wb;            off = i8 - NX; }
        else if (i8 < NX + 2 * NW) { src = wk; dst = wb + 1048576;  off = i8 - NX - NW; }
        else if (i8 < NX + 3 * NW) { src = wv; dst = wb + 2097152;  off = i8 - NX - 2 * NW; }
        else                       { src = er; dst = erb;           off = i8 - NX - 3 * NW; }
        ((bf16x8*)dst)[off] = load8f_to_bf(src + (size_t)off * 8);
    }
}

// ---------------------------------------------------------------------------
// Kernel 1 (fast path): QKV projection, m97-structure LDS-staged GEMM.
// (unchanged from r13 — dropped out of top-5 at ~30us)
// ---------------------------------------------------------------------------
__global__ __launch_bounds__(256) void proj_kernel_bf(
    const unsigned short* __restrict__ xb, const unsigned short* __restrict__ wb,
    unsigned short* __restrict__ Qb, unsigned short* __restrict__ Kb,
    unsigned short* __restrict__ Vt)
{
    __shared__ __align__(16) unsigned short Al[128 * 64];   // 16 KB
    __shared__ __align__(16) unsigned short Bl[128 * 64];   // 16 KB

    const int tid  = threadIdx.x;
    const int lane = tid & 63;
    const int w    = tid >> 6;
    const int wr   = w >> 1;
    const int wc   = w & 1;
    const int m0   = blockIdx.x * 128;
    const int c0   = blockIdx.y * 128;
    const int wsel = c0 >> 10;
    const int f0   = c0 & 1023;
    const unsigned short* __restrict__ W = wb + (size_t)wsel * 1048576;

    const int lr = lane & 15;
    const int g  = lane >> 4;

    const int srow8 = tid >> 3;                           // 0..31
    const int scol  = (((tid & 7) ^ (srow8 & 7))) * 8;    // pre-swizzled, elems

    f32x4 acc[4][4];
#pragma unroll
    for (int i = 0; i < 4; i++)
#pragma unroll
        for (int n = 0; n < 4; n++) acc[i][n] = (f32x4){0.f, 0.f, 0.f, 0.f};

    for (int k0 = 0; k0 < 1024; k0 += 64) {
        __syncthreads();   // WAR: previous step's LDS reads complete
#pragma unroll
        for (int i = 0; i < 4; i++) {
            gload_lds16(&xb[(size_t)(m0 + i * 32 + srow8) * 1024 + k0 + scol],
                        &Al[(i * 4 + w) * 512]);
            gload_lds16(&W [(size_t)(f0 + i * 32 + srow8) * 1024 + k0 + scol],
                        &Bl[(i * 4 + w) * 512]);
        }
        __syncthreads();   // RAW: barrier drains vmcnt -> stage visible

#pragma unroll
        for (int kk = 0; kk < 2; kk++) {
            bf16x8 a[4], b[4];
#pragma unroll
            for (int i = 0; i < 4; i++) {
                int ar = wr * 64 + i * 16 + lr;
                a[i] = *(const bf16x8*)&Al[ar * 64 + (((kk * 4 + g) ^ (ar & 7)) * 8)];
            }
#pragma unroll
            for (int n = 0; n < 4; n++) {
                int br = wc * 64 + n * 16 + lr;
                b[n] = *(const bf16x8*)&Bl[br * 64 + (((kk * 4 + g) ^ (br & 7)) * 8)];
            }
#pragma unroll
            for (int i = 0; i < 4; i++)
#pragma unroll
                for (int n = 0; n < 4; n++)
                    acc[i][n] = __builtin_amdgcn_mfma_f32_16x16x32_bf16(a[i], b[n], acc[i][n], 0, 0, 0);
        }
    }

#pragma unroll
    for (int i = 0; i < 4; i++) {
#pragma unroll
        for (int n = 0; n < 4; n++) {
#pragma unroll
            for (int j = 0; j < 4; j++) {
                int row_m = m0 + wr * 64 + i * 16 + g * 4 + j;
                int c     = c0 + wc * 64 + n * 16 + lr;
                int f     = c & 1023;
                int h     = f >> 6;
                int dd    = f & 63;
                int bb    = row_m >> 11;
                int s     = row_m & 2047;
                int bh    = bb * 16 + h;
                unsigned short bv = f2bf(acc[i][n][j]);
                if (wsel == 0)      Qb[((size_t)bh * 2048 + s) * 64 + dd] = bv;
                else if (wsel == 1) Kb[((size_t)bh * 2048 + s) * 64 + dd] = bv;
                else                Vt[((size_t)bh * 64 + dd) * 2048 + s] = bv;
            }
        }
    }
}

// ---------------------------------------------------------------------------
// Kernel 1 (fallback): f32 inputs with in-loop convert (direct loads).
// ---------------------------------------------------------------------------
__global__ __launch_bounds__(256) void proj_kernel_f32(
    const float* __restrict__ x,
    const float* __restrict__ Wq, const float* __restrict__ Wk,
    const float* __restrict__ Wv,
    unsigned short* __restrict__ Qb, unsigned short* __restrict__ Kb,
    unsigned short* __restrict__ Vt)
{
    const int tid  = threadIdx.x;
    const int lane = tid & 63;
    const int w    = tid >> 6;
    const int wr   = w >> 1;
    const int wc   = w & 1;
    const int m0   = blockIdx.x * 128 + wr * 64;
    const int c0   = blockIdx.y * 128 + wc * 64;
    const int wsel = c0 >> 10;
    const int f0   = c0 & 1023;
    const float* __restrict__ W = (wsel == 0) ? Wq : (wsel == 1) ? Wk : Wv;

    const int lr = lane & 15;
    const int lk = (lane >> 4) * 8;

    f32x4 acc[4][4];
#pragma unroll
    for (int i = 0; i < 4; i++)
#pragma unroll
        for (int n = 0; n < 4; n++) acc[i][n] = (f32x4){0.f, 0.f, 0.f, 0.f};

    for (int k0 = 0; k0 < 1024; k0 += 32) {
        bf16x8 a[4], b[4];
#pragma unroll
        for (int i = 0; i < 4; i++)
            a[i] = load8f_to_bf(&x[(size_t)(m0 + i * 16 + lr) * 1024 + k0 + lk]);
#pragma unroll
        for (int n = 0; n < 4; n++)
            b[n] = load8f_to_bf(&W[(size_t)(f0 + n * 16 + lr) * 1024 + k0 + lk]);
#pragma unroll
        for (int i = 0; i < 4; i++)
#pragma unroll
            for (int n = 0; n < 4; n++)
                acc[i][n] = __builtin_amdgcn_mfma_f32_16x16x32_bf16(a[i], b[n], acc[i][n], 0, 0, 0);
    }

    const int g = lane >> 4;
#pragma unroll
    for (int i = 0; i < 4; i++) {
#pragma unroll
        for (int n = 0; n < 4; n++) {
#pragma unroll
            for (int j = 0; j < 4; j++) {
                int row_m = m0 + i * 16 + g * 4 + j;
                int c     = c0 + n * 16 + lr;
                int f     = c & 1023;
                int h     = f >> 6;
                int dd    = f & 63;
                int bb    = row_m >> 11;
                int s     = row_m & 2047;
                int bh    = bb * 16 + h;
                unsigned short bv = f2bf(acc[i][n][j]);
                if (wsel == 0)      Qb[((size_t)bh * 2048 + s) * 64 + dd] = bv;
                else if (wsel == 1) Kb[((size_t)bh * 2048 + s) * 64 + dd] = bv;
                else                Vt[((size_t)bh * 64 + dd) * 2048 + s] = bv;
            }
        }
    }
}

__global__ void cvt_er(const float* __restrict__ Er, unsigned short* __restrict__ Erb, int n)
{
    int i = blockIdx.x * 256 + threadIdx.x;
    if (i < n) Erb[i] = f2bf(Er[i]);
}

// ---------------------------------------------------------------------------
// Kernel 2: flash attention — 4-wave blocks, LDS-staged K/V/Er.
// r14 changes vs r13 (attn was VALU-bound: 47% VALUBusy, 16% MfmaUtil):
//  (1) causal mask only on diagonal tile (kt==qt); kt<qt provably unmasked.
//  (2) P packed via native __float2bfloat16 (was 4-op manual round).
//  (3) El is a 128-slot RING: window slides +64 rows/tile -> stage only the
//      64 new rows (2 chunks, was 4). slot = abs_row & 127; write happens
//      after barrier A so slot reuse never races reads; read offset
//      ep = 64*((qt^kt^1)&1); swizzle bits (abs&7) unchanged by &127.
//  (4) T5 setprio(1) around MFMA clusters.
// ---------------------------------------------------------------------------
__global__ __launch_bounds__(256) void attn_kernel(
    const unsigned short* __restrict__ Qb, const unsigned short* __restrict__ Kb,
    const unsigned short* __restrict__ Vt, const unsigned short* __restrict__ Erb,
    float* __restrict__ out)
{
    __shared__ __align__(16) unsigned short Kl[64 * 64];
    __shared__ __align__(16) unsigned short Vl[64 * 64];
    __shared__ __align__(16) unsigned short El[128 * 64];
    __shared__ __align__(16) float          Rt[4][80][18];

    const int tid  = threadIdx.x;
    const int lane = tid & 63;
    const int w    = tid >> 6;

    const int i0  = blockIdx.x;
    const int xcd = i0 & 7;              // XCD pin: bh in {4*xcd..4*xcd+3}
    const int b2  = (i0 >> 3) & 3;
    const int qt  = 31 - (i0 >> 5);      // heavy first
    const int bh  = (xcd << 2) | b2;

    const int lr = lane & 15;
    const int g  = lane >> 4;
    const int lk = g * 8;

    const unsigned short* __restrict__ Qrow = Qb + (size_t)bh * 2048 * 64;
    const unsigned short* __restrict__ Krow = Kb + (size_t)bh * 2048 * 64;
    const unsigned short* __restrict__ Vrow = Vt + (size_t)bh * 64 * 2048;

    const float SCL = 0.125f * 1.44269504089f;  // (1/sqrt(64)) * log2(e)
    const int bb  = bh >> 4;
    const int h   = bh & 15;
    const int q0  = qt * 64;
    const int q0w = q0 + w * 16;
    const int eoff = 48 - 16 * w;               // strip-w window base (rel)
    const int rbT0 = 1984 - q0;                 // abs row of tile-0 window

    bf16x8 aq[2];
#pragma unroll
    for (int kk = 0; kk < 2; kk++)
        aq[kk] = *(const bf16x8*)&Qrow[(size_t)(q0w + lr) * 64 + kk * 32 + lk];

    f32x4 o[4];
#pragma unroll
    for (int m = 0; m < 4; m++) o[m] = (f32x4){0.f, 0.f, 0.f, 0.f};
    float mrow = -1e30f, lsum = 0.f;

    // ---- T14 stage registers ----
    bf16x8 sk[2], sv[2], se[4];
    const int o8u = (tid & 7) * 8;

    auto kv_load = [&](int kt) {
        const int k0 = kt * 64;
#pragma unroll
        for (int i = 0; i < 2; i++) {
            int kr = ((i * 256 + tid) >> 3);
            sk[i] = *(const bf16x8*)&Krow[(size_t)(k0 + kr) * 64 + o8u];
        }
#pragma unroll
        for (int i = 0; i < 2; i++) {
            int d = ((i * 256 + tid) >> 3);
            sv[i] = *(const bf16x8*)&Vrow[(size_t)d * 2048 + k0 + o8u];
        }
    };
    auto kv_write = [&]() {
#pragma unroll
        for (int i = 0; i < 2; i++) {
            int kr = ((i * 256 + tid) >> 3);
            *(bf16x8*)&Kl[(kr * 64 + o8u) ^ ((kr & 7) << 3)] = sk[i];
        }
#pragma unroll
        for (int i = 0; i < 2; i++) {
            int d = ((i * 256 + tid) >> 3);
            *(bf16x8*)&Vl[(d * 64 + o8u) ^ ((d & 7) << 3)] = sv[i];
        }
    };
    // Er ring: load rows base..base+127 (4ch) or base..base+63 (2ch)
    auto e_load4 = [&](int base) {
#pragma unroll
        for (int i = 0; i < 4; i++) {
            int r = base + ((i * 256 + tid) >> 3);
            int rr = r > 2047 ? 2047 : r;
            se[i] = *(const bf16x8*)&Erb[(size_t)rr * 64 + o8u];
        }
    };
    auto e_load2 = [&](int base) {
#pragma unroll
        for (int i = 0; i < 2; i++) {
            int r = base + ((i * 256 + tid) >> 3);
            int rr = r > 2047 ? 2047 : r;
            se[i] = *(const bf16x8*)&Erb[(size_t)rr * 64 + o8u];
        }
    };
    auto e_write4 = [&](int base) {
#pragma unroll
        for (int i = 0; i < 4; i++) {
            int r = base + ((i * 256 + tid) >> 3);
            int slot = r & 127;
            *(bf16x8*)&El[(slot * 64 + o8u) ^ ((slot & 7) << 3)] = se[i];
        }
    };
    auto e_write2 = [&](int base) {
#pragma unroll
        for (int i = 0; i < 2; i++) {
            int r = base + ((i * 256 + tid) >> 3);
            int slot = r & 127;
            *(bf16x8*)&El[(slot * 64 + o8u) ^ ((slot & 7) << 3)] = se[i];
        }
    };

    kv_load(0);
    e_load4(rbT0);

#pragma unroll 1
    for (int kt = 0; kt <= qt; ++kt) {
        const int k0 = kt * 64;
        const int ep = ((qt ^ kt ^ 1) & 1) << 6;   // ring parity offset

        bar_lds();                 // A: prior tile's LDS reads done (WAR)
        kv_write();
        if (kt == 0) e_write4(rbT0);
        else         e_write2(rbT0 + 64 * kt + 64);
        if (kt < qt) {
            kv_load(kt + 1);
            e_load2(rbT0 + 64 * kt + 128);   // next tile's new 64 rows
        }
        bar_lds();                 // B: stage visible to all waves

        // ---- S^T = K·Q^T and R^T = Er·Q^T (frags from LDS) ----
        f32x4 s[4], r[5];
#pragma unroll
        for (int n = 0; n < 4; n++) s[n] = (f32x4){0.f, 0.f, 0.f, 0.f};
#pragma unroll
        for (int n = 0; n < 5; n++) r[n] = (f32x4){0.f, 0.f, 0.f, 0.f};
        __builtin_amdgcn_s_setprio(1);
#pragma unroll
        for (int kk = 0; kk < 2; kk++) {
            bf16x8 kb[4], be[5];
#pragma unroll
            for (int n = 0; n < 4; n++) {
                int kr = n * 16 + lr;
                kb[n] = *(const bf16x8*)&Kl[(kr * 64 + kk * 32 + lk) ^ ((kr & 7) << 3)];
            }
#pragma unroll
            for (int n = 0; n < 5; n++) {
                int er = (eoff + n * 16 + lr + ep) & 127;
                be[n] = *(const bf16x8*)&El[(er * 64 + kk * 32 + lk) ^ ((er & 7) << 3)];
            }
#pragma unroll
            for (int n = 0; n < 4; n++)
                s[n] = __builtin_amdgcn_mfma_f32_16x16x32_bf16(kb[n], aq[kk], s[n], 0, 0, 0);
#pragma unroll
            for (int n = 0; n < 5; n++)
                r[n] = __builtin_amdgcn_mfma_f32_16x16x32_bf16(be[n], aq[kk], r[n], 0, 0, 0);
        }
        __builtin_amdgcn_s_setprio(0);

        // ---- Rt skew exchange (per-wave region) ----
#pragma unroll
        for (int n = 0; n < 5; n++)
#pragma unroll
            for (int j = 0; j < 4; j++)
                Rt[w][n * 16 + g * 4 + j][lr] = r[n][j];

        bar_lds();                 // C: Rt RAW (also compiler fence, rule 18)

        // ---- combine (+ mask only on the diagonal tile) ----
        float pmax = -1e30f;
        if (kt != qt) {
#pragma unroll
            for (int n = 0; n < 4; n++)
#pragma unroll
                for (int j = 0; j < 4; j++) {
                    int wd = n * 16 + g * 4 + j + 15 - lr;
                    float sc = (s[n][j] + Rt[w][wd][lr]) * SCL;
                    s[n][j] = sc;
                    pmax = fmaxf(pmax, sc);
                }
        } else {
#pragma unroll
            for (int n = 0; n < 4; n++)
#pragma unroll
                for (int j = 0; j < 4; j++) {
                    int kl = n * 16 + g * 4 + j;
                    int wd = kl + 15 - lr;
                    float sc = (s[n][j] + Rt[w][wd][lr]) * SCL;
                    if (kl > w * 16 + lr) sc = -1e30f;   // k0==q0: klocal > qlocal
                    s[n][j] = sc;
                    pmax = fmaxf(pmax, sc);
                }
        }

        // ---- T13: reduce + rescale only when the row max grows ----
        if (__any(pmax > mrow + 4.0f)) {
            pmax = fmaxf(pmax, __shfl_xor(pmax, 16));
            pmax = fmaxf(pmax, __shfl_xor(pmax, 32));
            float mn   = fmaxf(mrow, pmax);
            float corr = exp2f(mrow - mn);
            mrow = mn;
            lsum *= corr;
#pragma unroll
            for (int j = 0; j < 4; j++) {
                float cj = __shfl(corr, g * 4 + j);
#pragma unroll
                for (int m = 0; m < 4; m++) o[m][j] *= cj;
            }
        }

        // ---- exp + pack P into A-fragments (native cvt) ----
        float rs = 0.f;
        bf16x4 pa[4];
#pragma unroll
        for (int n = 0; n < 4; n++)
#pragma unroll
            for (int j = 0; j < 4; j++) {
                float pv = exp2f(s[n][j] - mrow);
                rs += pv;
                pa[n][j] = f2bf_fast(pv);
            }
        lsum += rs;

        // ---- P @ V : V B-fragments from LDS ----
        __builtin_amdgcn_s_setprio(1);
#pragma unroll
        for (int m = 0; m < 4; m++) {
#pragma unroll
            for (int n = 0; n < 4; n++) {
                int d = 16 * m + lr;
                bf16x4 vb = *(const bf16x4*)&Vl[(d * 64 + 16 * n + 4 * g) ^ ((d & 7) << 3)];
                o[m] = __builtin_amdgcn_mfma_f32_16x16x16bf16_1k(pa[n], vb, o[m], 0, 0, 0);
            }
        }
        __builtin_amdgcn_s_setprio(0);
    }

    // ---- epilogue: reduce partial lsum over g-lanes, store f32 ----
    float ls = lsum;
    ls += __shfl_xor(ls, 16);
    ls += __shfl_xor(ls, 32);
    float linv = 1.0f / ls;
#pragma unroll
    for (int j = 0; j < 4; j++) {
        float lj = __shfl(linv, g * 4 + j);
#pragma unroll
        for (int m = 0; m < 4; m++) {
            int row = q0w + g * 4 + j;
            int col = h * 64 + 16 * m + lr;
            out[((size_t)bb * 2048 + row) * 1024 + col] = o[m][j] * lj;
        }
    }
}

// ---------------------------------------------------------------------------
extern "C" void kernel_launch(void* const* d_in, const int* in_sizes, int n_in,
                              void* d_out, int out_size, void* d_ws, size_t ws_size,
                              hipStream_t stream)
{
    const float* x  = (const float*)d_in[0];
    const float* Wq = (const float*)d_in[1];
    const float* Wk = (const float*)d_in[2];
    const float* Wv = (const float*)d_in[3];
    const float* Er = (const float*)d_in[4];
    float* out = (float*)d_out;   // f32 output (reference returns jnp.float32)

    char* ws = (char*)d_ws;
    const size_t MB = 1024 * 1024;
    unsigned short* Qb  = (unsigned short*)(ws);            // 8 MB
    unsigned short* Kb  = (unsigned short*)(ws + 8  * MB);  // 8 MB
    unsigned short* Vt  = (unsigned short*)(ws + 16 * MB);  // 8 MB
    unsigned short* Erb = (unsigned short*)(ws + 24 * MB);  // 256 KB
    unsigned short* xb  = (unsigned short*)(ws + 25 * MB);  // 8 MB
    unsigned short* wb  = (unsigned short*)(ws + 33 * MB);  // 6 MB  (total 39 MB)

    if (ws_size >= (size_t)39 * MB) {
        cvt_bf16<<<dim3(1024), dim3(256), 0, stream>>>(x, Wq, Wk, Wv, Er, xb, wb, Erb);
        proj_kernel_bf<<<dim3(32, 24), dim3(256), 0, stream>>>(xb, wb, Qb, Kb, Vt);
    } else {
        cvt_er<<<dim3(512), dim3(256), 0, stream>>>(Er, Erb, 2048 * 64);
        proj_kernel_f32<<<dim3(32, 24), dim3(256), 0, stream>>>(x, Wq, Wk, Wv, Qb, Kb, Vt);
    }
    attn_kernel<<<dim3(1024), dim3(256), 0, stream>>>(Qb, Kb, Vt, Erb, out);
}